// Round 8
// baseline (341.551 us; speedup 1.0000x reference)
//
#include <hip/hip_runtime.h>
#include <stdint.h>
#include <math.h>

// cdist-attention, bf16 MFMA pipeline == R6 exactly (244 µs best), PLUS one
// ablation probe (R8): probe_nostage = R7's 128x128 scores kernel with
// global_load_lds+vmcnt DELETED (ds_read via inline asm so the loop-invariant
// reads can't be hoisted), 2 full K-passes, writing E before the real scores
// dispatch overwrites it. T_probe = dur_us - 244 splits the world:
//   staging-delivery-bound (m177)  -> T_probe ~ 60-110 us
//   compute/barrier-chain-bound    -> T_probe ~ 230-270 us (tops rocprof table)
// Five falsified single-mechanism theories (R2-R7) => measure, don't guess.

typedef __attribute__((ext_vector_type(8))) __bf16 bf16x8;
typedef __attribute__((ext_vector_type(4))) float f32x4;

__device__ __forceinline__ unsigned short f2b(float f) {
    unsigned u = __float_as_uint(f);
    unsigned r = 0x7fffu + ((u >> 16) & 1u);
    return (unsigned short)((u + r) >> 16);
}
__device__ __forceinline__ float b2f(unsigned short h) {
    return __uint_as_float(((unsigned)h) << 16);
}

__device__ __forceinline__ void wg_barrier() {
    asm volatile("" ::: "memory");
    __builtin_amdgcn_s_barrier();
    asm volatile("" ::: "memory");
}

__device__ __forceinline__ void glds16(const unsigned short* src, unsigned short* dst) {
    __builtin_amdgcn_global_load_lds(
        (const __attribute__((address_space(1))) unsigned int*)src,
        (__attribute__((address_space(3))) unsigned int*)dst, 16, 0, 0);
}

__device__ __forceinline__ unsigned lds_off(const void* p) {
    return (unsigned)(uintptr_t)(const __attribute__((address_space(3))) char*)p;
}

__global__ __launch_bounds__(256) void castk(const float* __restrict__ src,
                                             unsigned short* __restrict__ dst, int n4) {
    int i = blockIdx.x * 256 + threadIdx.x;
    if (i >= n4) return;
    float4 v = ((const float4*)src)[i];
    ushort4 o;
    o.x = f2b(v.x); o.y = f2b(v.y); o.z = f2b(v.z); o.w = f2b(v.w);
    ((ushort4*)dst)[i] = o;
}

// MODE 0: row sum; MODE 1: row sum of squares. One wave per row.
template <int MODE>
__global__ __launch_bounds__(256) void rowreduce(const unsigned short* __restrict__ X,
                                                 int L, int rows, float* __restrict__ out) {
    int w = threadIdx.x >> 6, lane = threadIdx.x & 63;
    int row = blockIdx.x * 4 + w;
    if (row >= rows) return;
    const unsigned short* xr = X + (size_t)row * L;
    float s = 0.f;
    int passes = L >> 8;
    for (int p = 0; p < passes; ++p) {
        ushort4 u = *(const ushort4*)(xr + (p << 8) + lane * 4);
        float a = b2f(u.x), b = b2f(u.y), c = b2f(u.z), d = b2f(u.w);
        s += MODE ? (a * a + b * b + c * c + d * d) : (a + b + c + d);
    }
#pragma unroll
    for (int o = 32; o > 0; o >>= 1) s += __shfl_down(s, o);
    if (lane == 0) out[row] = s;
}

#define MF(A_, B_, C_) (C_) = __builtin_amdgcn_mfma_f32_16x16x32_bf16((A_), (B_), (C_), 0, 0, 0)
#define DSR(dst_, a_, imm_) \
    asm volatile("ds_read_b128 %0, %1 offset:" #imm_ : "=v"(dst_) : "v"(a_))
#define LGKM(n_) asm volatile("s_waitcnt lgkmcnt(" #n_ ")" ::: "memory")
#define VMC6 asm volatile("s_waitcnt vmcnt(6)" ::: "memory")
#define VMC0 asm volatile("s_waitcnt vmcnt(0)" ::: "memory")
#define SB0 __builtin_amdgcn_sched_barrier(0)
#define NOPS ((void)0)

#define CLUSTER(MI0_, NI0_, AARR_, BARR_)                                  \
    _Pragma("unroll") for (int mi_ = 0; mi_ < 4; ++mi_) {                  \
        _Pragma("unroll") for (int ni_ = 0; ni_ < 2; ++ni_) {              \
            MF(AARR_[mi_][0], BARR_[ni_][0], acc[(MI0_) + mi_][(NI0_) + ni_]); \
            MF(AARR_[mi_][1], BARR_[ni_][1], acc[(MI0_) + mi_][(NI0_) + ni_]); \
        }                                                                  \
    }

// One K-tile = 4 phases. S1..S4 are staging statements; VMW_ the boundary wait.
#define TILE(A0_, A0X_, B0_, B0X_, S1_, S2_, S3_, S4_, VMW_) do {          \
    DSR(aF[0][0], A0_, 0);    DSR(aF[0][1], A0X_, 0);                      \
    DSR(aF[1][0], A0_, 2048); DSR(aF[1][1], A0X_, 2048);                   \
    DSR(aF[2][0], A0_, 4096); DSR(aF[2][1], A0X_, 4096);                   \
    DSR(aF[3][0], A0_, 6144); DSR(aF[3][1], A0X_, 6144);                   \
    DSR(bL[0][0], B0_, 0);    DSR(bL[0][1], B0X_, 0);                      \
    DSR(bL[1][0], B0_, 2048); DSR(bL[1][1], B0X_, 2048);                   \
    S1_;                                                                   \
    LGKM(8);                                                               \
    wg_barrier();                                                          \
    LGKM(0); SB0;                                                          \
    __builtin_amdgcn_s_setprio(1);                                         \
    CLUSTER(0, 0, aF, bL)                                                  \
    SB0; __builtin_amdgcn_s_setprio(0);                                    \
    wg_barrier();                                                          \
    DSR(bH[0][0], B0_, 4096); DSR(bH[0][1], B0X_, 4096);                   \
    DSR(bH[1][0], B0_, 6144); DSR(bH[1][1], B0X_, 6144);                   \
    S2_;                                                                   \
    wg_barrier();                                                          \
    LGKM(0); SB0;                                                          \
    __builtin_amdgcn_s_setprio(1);                                         \
    CLUSTER(0, 2, aF, bH)                                                  \
    SB0; __builtin_amdgcn_s_setprio(0);                                    \
    wg_barrier();                                                          \
    DSR(aH[0][0], A0_, 8192);  DSR(aH[0][1], A0X_, 8192);                  \
    DSR(aH[1][0], A0_, 10240); DSR(aH[1][1], A0X_, 10240);                 \
    DSR(aH[2][0], A0_, 12288); DSR(aH[2][1], A0X_, 12288);                 \
    DSR(aH[3][0], A0_, 14336); DSR(aH[3][1], A0X_, 14336);                 \
    S3_;                                                                   \
    wg_barrier();                                                          \
    LGKM(0); SB0;                                                          \
    __builtin_amdgcn_s_setprio(1);                                         \
    CLUSTER(4, 2, aH, bH)                                                  \
    SB0; __builtin_amdgcn_s_setprio(0);                                    \
    wg_barrier();                                                          \
    S4_;                                                                   \
    VMW_;                                                                  \
    wg_barrier();                                                          \
    SB0;                                                                   \
    __builtin_amdgcn_s_setprio(1);                                         \
    CLUSTER(4, 0, aH, bL)                                                  \
    SB0; __builtin_amdgcn_s_setprio(0);                                    \
    wg_barrier();                                                          \
} while (0)

// Stage A-half H of K-tile T into buffer BUF (64-row interleave).
#define SA_(T_, BUF_, H_) do {                                             \
    const unsigned short* s_ = pA0 + (size_t)((H_) * 64) * lda + (size_t)(T_) * 64; \
    unsigned short* d_ = As + (BUF_) * 16384 + (H_) * 4096 + tid * 8;      \
    glds16(s_, d_);                                                        \
    glds16(s_ + (size_t)128 * lda, d_ + 8192);                             \
} while (0)
// Stage B-half H (32-row interleave).
#define SBs_(T_, BUF_, H_) do {                                            \
    const unsigned short* s_ = pB0 + (size_t)((H_) * 32) * ldb + (size_t)(T_) * 64; \
    unsigned short* d_ = Bs + (BUF_) * 16384 + (H_) * 2048 + dB0 + tid * 8; \
    glds16(s_, d_);                                                        \
    glds16(s_ + (size_t)128 * ldb, d_ + 8192);                             \
} while (0)

// C[m][n] = sum_k A[m][k]*B[n][k].
// perm=0: (x=colTile, y=rowTile, z=batch). perm=1: (x=batch, y=colTile,
// z=rowTile) -> round-robin wg->XCD gives XCD i all blocks of batch i.
// EPI 0: store bf16.  EPI 1: scores epilogue.  EPI 2: store f32 = acc/aux1[row].
template <int EPI>
__global__ __launch_bounds__(512, 2) void gemm256(
    const unsigned short* __restrict__ A, int lda, long long sA,
    const unsigned short* __restrict__ B, int ldb, long long sB,
    void* __restrict__ Cv, int ldc, long long sC,
    int Kd, int perm,
    const float* __restrict__ aux1, int sAux1,
    const float* __restrict__ aux2, int sAux2,
    float invs) {
    __shared__ __attribute__((aligned(128))) unsigned short As[2 * 256 * 64];
    __shared__ __attribute__((aligned(128))) unsigned short Bs[2 * 256 * 64];

    const int z = perm ? blockIdx.x : blockIdx.z;
    const int jb = perm ? blockIdx.y : blockIdx.x;
    const int ib = perm ? blockIdx.z : blockIdx.y;
    const unsigned short* __restrict__ Ab = A + (size_t)z * sA;
    const unsigned short* __restrict__ Bb = B + (size_t)z * sB;
    const int i0 = ib * 256;
    const int j0 = jb * 256;
    const int tid = threadIdx.x;
    const int w = tid >> 6, lane = tid & 63;
    const int wr = w >> 2, wc = w & 3;          // 2 x 4 wave grid
    const int c16 = lane & 15, kq = lane >> 4;  // frag col / k-octet

    // staging source (pre-swizzled global chunk; LDS dst stays linear)
    const int lr0 = tid >> 3;                    // 0..63
    const int clog0 = (tid & 7) ^ (lr0 & 7);     // logical 16B chunk
    const unsigned short* pA0 = Ab + (size_t)(i0 + lr0) * lda + clog0 * 8;
    const unsigned short* pB0 = Bb + (size_t)(j0 + lr0 + (lr0 & 32)) * ldb + clog0 * 8;
    const int dB0 = (tid & 256) << 3;  // +2048 shorts for tid>=256 (row group +64)

    // frag read bases (swizzled): stored chunk = (kk*4+kq) ^ (row&7); row&7==c16&7
    const int swc = (kq ^ (c16 & 7)) << 4;
    const unsigned adrA0 = lds_off(As) + (unsigned)(wr * 128 + c16) * 128 + swc;
    const unsigned adrA0x = adrA0 ^ 64u;
    const unsigned adrA1 = adrA0 + 32768u, adrA1x = adrA0x + 32768u;
    const unsigned adrB0 = lds_off(Bs) + (unsigned)(wc * 64 + c16) * 128 + swc;
    const unsigned adrB0x = adrB0 ^ 64u;
    const unsigned adrB1 = adrB0 + 32768u, adrB1x = adrB0x + 32768u;

    f32x4 acc[8][4];
    const f32x4 zero = {0.f, 0.f, 0.f, 0.f};
#pragma unroll
    for (int i = 0; i < 8; ++i)
#pragma unroll
        for (int j = 0; j < 4; ++j) acc[i][j] = zero;

    bf16x8 aF[4][2], aH[4][2], bL[2][2], bH[2][2];

    const int npairs = Kd >> 7;  // BK=64 tile pairs; requires Kd % 128 == 0, >= 2

    // prologue: tile0 all 4 halves (buf0); tile1 Ah0,Bh0,Ah1 (buf1); vmcnt(6)
    SA_(0, 0, 0); SA_(0, 0, 1); SBs_(0, 0, 0); SBs_(0, 0, 1);
    SA_(1, 1, 0); SBs_(1, 1, 0); SA_(1, 1, 1);
    VMC6;
    wg_barrier();

    for (int u = 0; u < npairs - 1; ++u) {
        const int t0 = 2 * u;
        TILE(adrA0, adrA0x, adrB0, adrB0x,
             SBs_(t0 + 1, 1, 1), SA_(t0 + 2, 0, 0), SBs_(t0 + 2, 0, 0), SA_(t0 + 2, 0, 1),
             VMC6);
        TILE(adrA1, adrA1x, adrB1, adrB1x,
             SBs_(t0 + 2, 0, 1), SA_(t0 + 3, 1, 0), SBs_(t0 + 3, 1, 0), SA_(t0 + 3, 1, 1),
             VMC6);
    }
    {   // tail pair: finish Bh1(last tile); drain; last tile pure compute
        const int t0 = 2 * npairs - 2;
        TILE(adrA0, adrA0x, adrB0, adrB0x,
             SBs_(t0 + 1, 1, 1), NOPS, NOPS, NOPS, VMC0);
        TILE(adrA1, adrA1x, adrB1, adrB1x, NOPS, NOPS, NOPS, NOPS, NOPS);
    }

    // C/D layout: col = lane&15, row = (lane>>4)*4 + reg
    const int r4 = kq * 4;
    if constexpr (EPI == 0) {
        unsigned short* C = (unsigned short*)Cv + (size_t)z * sC;
#pragma unroll
        for (int mi = 0; mi < 8; ++mi)
#pragma unroll
            for (int ni = 0; ni < 4; ++ni) {
                const int row = i0 + wr * 128 + mi * 16 + r4;
                const int col = j0 + wc * 64 + ni * 16 + c16;
#pragma unroll
                for (int r = 0; r < 4; ++r)
                    C[(size_t)(row + r) * ldc + col] = f2b(acc[mi][ni][r]);
            }
    } else if constexpr (EPI == 1) {
        unsigned short* C = (unsigned short*)Cv + (size_t)z * sC;
        const float* q2b = aux1 + (size_t)z * sAux1;
        const float* k2b = aux2 + (size_t)z * sAux2;
#pragma unroll
        for (int mi = 0; mi < 8; ++mi)
#pragma unroll
            for (int ni = 0; ni < 4; ++ni) {
                const int row = i0 + wr * 128 + mi * 16 + r4;
                const int col = j0 + wc * 64 + ni * 16 + c16;
                const float k2v = k2b[col];
#pragma unroll
                for (int r = 0; r < 4; ++r) {
                    float d2 = q2b[row + r] + k2v - 2.0f * acc[mi][ni][r];
                    float e = __expf(sqrtf(fmaxf(d2, 0.f)) * invs);
                    C[(size_t)(row + r) * ldc + col] = f2b(e);
                }
            }
    } else {
        float* C = (float*)Cv + (size_t)z * sC;
        const float* lb = aux1 + (size_t)z * sAux1;
#pragma unroll
        for (int mi = 0; mi < 8; ++mi)
#pragma unroll
            for (int ni = 0; ni < 4; ++ni) {
                const int row = i0 + wr * 128 + mi * 16 + r4;
                const int col = j0 + wc * 64 + ni * 16 + c16;
#pragma unroll
                for (int r = 0; r < 4; ++r)
                    C[(size_t)(row + r) * ldc + col] = acc[mi][ni][r] / lb[row + r];
            }
    }
}

// ======================= R8 ABLATION PROBE =======================
// R7's 128x128 scores kernel with STAGING DELETED: no global_load_lds, no
// vmcnt. Inline-asm ds_read (non-hoistable) + lgkmcnt + both barriers + 16
// MFMA per tile + EPI1 epilogue all kept. 2 full K-passes. Reads whatever is
// in LDS (garbage) -> writes E, which the real scores dispatch then fully
// overwrites. T_probe = dur_us - 244 isolates staging-delivery cost.
__global__ __launch_bounds__(256) void probe_nostage(
    const unsigned short* __restrict__ A,
    const unsigned short* __restrict__ B,
    unsigned short* __restrict__ Cq,
    const float* __restrict__ q2a, const float* __restrict__ k2a, float invs) {
    __shared__ __attribute__((aligned(128))) unsigned short As[128 * 32];
    __shared__ __attribute__((aligned(128))) unsigned short Bs[128 * 32];
    const int S = 2048, F = 768;
    const int z = blockIdx.x, jb = blockIdx.y, ib = blockIdx.z;
    const int i0 = ib * 128, j0 = jb * 128;
    const int tid = threadIdx.x;
    const int w = tid >> 6, lane = tid & 63;
    const int wr = w >> 1, wc = w & 1;
    const int c16 = lane & 15, kq = lane >> 4;

    // same frag-read address pattern as R7 (conflict-free swizzle)
    const int sw8 = (kq ^ ((c16 >> 1) & 3)) << 3;
    const unsigned adrA = lds_off(As) + (unsigned)((wr * 64 + c16) * 32 + sw8) * 2;
    const unsigned adrB = lds_off(Bs) + (unsigned)((wc * 64 + c16) * 32 + sw8) * 2;

    f32x4 acc[4][4];
    const f32x4 zero = {0.f, 0.f, 0.f, 0.f};
#pragma unroll
    for (int a = 0; a < 4; ++a)
#pragma unroll
        for (int b = 0; b < 4; ++b) acc[a][b] = zero;

    const int nt = F >> 5;  // 24 K-tiles
    for (int rep = 0; rep < 2; ++rep) {
        for (int t = 0; t < nt; ++t) {
            // (staging + vmcnt deleted here)
            wg_barrier();
            bf16x8 af[4], bfv[4];
            DSR(af[0], adrA, 0);    DSR(af[1], adrA, 1024);
            DSR(af[2], adrA, 2048); DSR(af[3], adrA, 3072);
            DSR(bfv[0], adrB, 0);    DSR(bfv[1], adrB, 1024);
            DSR(bfv[2], adrB, 2048); DSR(bfv[3], adrB, 3072);
            LGKM(0); SB0;
            __builtin_amdgcn_s_setprio(1);
#pragma unroll
            for (int mi = 0; mi < 4; ++mi)
#pragma unroll
                for (int ni = 0; ni < 4; ++ni)
                    MF(af[mi], bfv[ni], acc[mi][ni]);
            SB0; __builtin_amdgcn_s_setprio(0);
            wg_barrier();
        }
    }

    const float* q2b = q2a + (size_t)z * S;
    const float* k2b = k2a + (size_t)z * S;
    unsigned short* C = Cq + (size_t)z * S * S;
    const int r4 = kq * 4;
#pragma unroll
    for (int mi = 0; mi < 4; ++mi)
#pragma unroll
        for (int ni = 0; ni < 4; ++ni) {
            const int row = i0 + wr * 64 + mi * 16 + r4;
            const int col = j0 + wc * 64 + ni * 16 + c16;
            const float k2v = k2b[col];
#pragma unroll
            for (int r = 0; r < 4; ++r) {
                float d2 = q2b[row + r] + k2v - 2.0f * acc[mi][ni][r];
                float e = __expf(sqrtf(fmaxf(d2, 0.f)) * invs);
                C[(size_t)(row + r) * S + col] = f2b(e);
            }
        }
    (void)A; (void)B;
}
// ================================================================

extern "C" void kernel_launch(void* const* d_in, const int* in_sizes, int n_in,
                              void* d_out, int out_size, void* d_ws, size_t ws_size,
                              hipStream_t stream) {
    const float* x = (const float*)d_in[0];
    const float* Wq = (const float*)d_in[1];
    const float* Wk = (const float*)d_in[2];
    const float* Wv = (const float*)d_in[3];
    const int Bz = 8, S = 2048, D = 768, F = 768;
    const int BS = Bz * S;  // 16384

    const size_t szX = (size_t)BS * D * 2;
    const size_t szW = (size_t)F * D * 2;
    const size_t szE = (size_t)Bz * S * S * 2;

    char* p = (char*)d_ws;
    unsigned short* xb = (unsigned short*)p;  p += szX;
    unsigned short* Wqb = (unsigned short*)p; p += szW;
    unsigned short* Wkb = (unsigned short*)p; p += szW;
    unsigned short* Wvb = (unsigned short*)p; p += szW;
    unsigned short* Qm = (unsigned short*)p;  p += szX;
    unsigned short* Km = (unsigned short*)p;  p += szX;
    unsigned short* VT = (unsigned short*)p;  p += szX;  // [F][BS]
    unsigned short* E = (unsigned short*)p;   p += szE;  // [Bz][S][S]
    float* q2 = (float*)p;   p += (size_t)BS * 4;
    float* k2 = (float*)p;   p += (size_t)BS * 4;
    float* lsum = (float*)p; p += (size_t)BS * 4;
    if ((size_t)(p - (char*)d_ws) > ws_size) return;  // ~164 MiB scratch required

    const float invs = 1.0f / sqrtf(768.0f);

    // 1) casts
    castk<<<(BS * D / 4 + 255) / 256, 256, 0, stream>>>(x, xb, BS * D / 4);
    castk<<<(F * D / 4 + 255) / 256, 256, 0, stream>>>(Wq, Wqb, F * D / 4);
    castk<<<(F * D / 4 + 255) / 256, 256, 0, stream>>>(Wk, Wkb, F * D / 4);
    castk<<<(F * D / 4 + 255) / 256, 256, 0, stream>>>(Wv, Wvb, F * D / 4);

    // 2) Q,K = x . W^T  (z=0 -> Wq, z=1 -> Wk); B=W is L2-resident, perm=0
    gemm256<0><<<dim3(F / 256, BS / 256, 2), 512, 0, stream>>>(
        xb, D, 0,
        Wqb, D, (long long)F * D,
        Qm, F, (long long)BS * F,
        D, 0, nullptr, 0, nullptr, 0, 0.f);

    //    V^T = Wv . x^T   -> VT[f][s]; perm=0
    gemm256<0><<<dim3(BS / 256, F / 256, 1), 512, 0, stream>>>(
        Wvb, D, 0,
        xb, D, 0,
        VT, BS, 0,
        D, 0, nullptr, 0, nullptr, 0, 0.f);

    // 3) row norms of Q,K
    rowreduce<1><<<BS / 4, 256, 0, stream>>>(Qm, F, BS, q2);
    rowreduce<1><<<BS / 4, 256, 0, stream>>>(Km, F, BS, k2);

    // --- R8 ablation probe (writes E; fully overwritten by real scores below)
    probe_nostage<<<dim3(Bz, S / 128, S / 128), 256, 0, stream>>>(
        Qm, Km, E, q2, k2, invs);

    // 4) E = exp(sqrt(max(q2+k2-2*Q.K^T,0))*invs); perm=1: XCD i owns batch i
    gemm256<1><<<dim3(Bz, S / 256, S / 256), 512, 0, stream>>>(
        Qm, F, (long long)S * F,
        Km, F, (long long)S * F,
        E, S, (long long)S * S,
        F, 1, q2, S, k2, S, invs);

    // 5) l = rowsum(E)
    rowreduce<0><<<BS / 4, 256, 0, stream>>>(E, S, BS, lsum);

    // 6) out = (E . V) / l; perm=1: XCD i reads the E_z it just wrote
    gemm256<2><<<dim3(Bz, F / 256, S / 256), 512, 0, stream>>>(
        E, S, (long long)S * S,
        VT, BS, (long long)S,
        d_out, F, (long long)S * F,
        S, 1, lsum, S, nullptr, 0, 0.f);
}

// Round 10
// 254.087 us; speedup vs baseline: 1.3442x; 1.3442x over previous
//
#include <hip/hip_runtime.h>
#include <stdint.h>
#include <math.h>

// cdist-attention, bf16 MFMA pipeline. R10 == R9 with the compile fix:
// inline-asm stage regs must be ext_vector_type (HIP's uint4 is a struct ->
// "indirect register inputs" error). REG-STAGED single-barrier GEMM:
// global_load_dwordx4 -> VGPR issued ONE FULL TILE AHEAD, vmcnt(0) (already
// landed) + ds_write_b128 into the other buffer, ONE raw s_barrier per tile.
// Same 256x256/BK=64/8-wave geometry, verified swizzle image + read
// addressing + epilogues + XCD perms as R6.

typedef __attribute__((ext_vector_type(8))) __bf16 bf16x8;
typedef __attribute__((ext_vector_type(4))) float f32x4;
typedef __attribute__((ext_vector_type(4))) unsigned int u32x4;

__device__ __forceinline__ unsigned short f2b(float f) {
    unsigned u = __float_as_uint(f);
    unsigned r = 0x7fffu + ((u >> 16) & 1u);
    return (unsigned short)((u + r) >> 16);
}
__device__ __forceinline__ float b2f(unsigned short h) {
    return __uint_as_float(((unsigned)h) << 16);
}

__device__ __forceinline__ void wg_barrier() {
    asm volatile("" ::: "memory");
    __builtin_amdgcn_s_barrier();
    asm volatile("" ::: "memory");
}

__device__ __forceinline__ unsigned lds_off(const void* p) {
    return (unsigned)(uintptr_t)(const __attribute__((address_space(3))) char*)p;
}

__global__ __launch_bounds__(256) void castk(const float* __restrict__ src,
                                             unsigned short* __restrict__ dst, int n4) {
    int i = blockIdx.x * 256 + threadIdx.x;
    if (i >= n4) return;
    float4 v = ((const float4*)src)[i];
    ushort4 o;
    o.x = f2b(v.x); o.y = f2b(v.y); o.z = f2b(v.z); o.w = f2b(v.w);
    ((ushort4*)dst)[i] = o;
}

// MODE 0: row sum; MODE 1: row sum of squares. One wave per row.
template <int MODE>
__global__ __launch_bounds__(256) void rowreduce(const unsigned short* __restrict__ X,
                                                 int L, int rows, float* __restrict__ out) {
    int w = threadIdx.x >> 6, lane = threadIdx.x & 63;
    int row = blockIdx.x * 4 + w;
    if (row >= rows) return;
    const unsigned short* xr = X + (size_t)row * L;
    float s = 0.f;
    int passes = L >> 8;
    for (int p = 0; p < passes; ++p) {
        ushort4 u = *(const ushort4*)(xr + (p << 8) + lane * 4);
        float a = b2f(u.x), b = b2f(u.y), c = b2f(u.z), d = b2f(u.w);
        s += MODE ? (a * a + b * b + c * c + d * d) : (a + b + c + d);
    }
#pragma unroll
    for (int o = 32; o > 0; o >>= 1) s += __shfl_down(s, o);
    if (lane == 0) out[row] = s;
}

#define MF(A_, B_, C_) (C_) = __builtin_amdgcn_mfma_f32_16x16x32_bf16((A_), (B_), (C_), 0, 0, 0)
#define DSR(dst_, a_, imm_) \
    asm volatile("ds_read_b128 %0, %1 offset:" #imm_ : "=v"(dst_) : "v"(a_))
#define GL4(d_, p_) asm volatile("global_load_dwordx4 %0, %1, off" : "=v"(d_) : "v"(p_))
#define DSW(a_, imm_, d_) \
    asm volatile("ds_write_b128 %0, %1 offset:" #imm_ :: "v"(a_), "v"(d_) : "memory")
#define LGKM(n_) asm volatile("s_waitcnt lgkmcnt(" #n_ ")" ::: "memory")
#define VMC0 asm volatile("s_waitcnt vmcnt(0)" ::: "memory")
#define SB0 __builtin_amdgcn_sched_barrier(0)

// issue one tile's 8 global loads (A rows lr0+{0,64,128,192}, B same) -> regs
#define LOADT(T_) do {                                                     \
    const size_t ko_ = (size_t)(T_) * 64;                                  \
    GL4(ra0, pa + ko_);             GL4(ra1, pa + lda64 + ko_);            \
    GL4(ra2, pa + 2 * lda64 + ko_); GL4(ra3, pa + 3 * lda64 + ko_);        \
    GL4(rb0, pb + ko_);             GL4(rb1, pb + ldb64 + ko_);            \
    GL4(rb2, pb + 2 * ldb64 + ko_); GL4(rb3, pb + 3 * ldb64 + ko_);        \
} while (0)
// write staged regs into LDS buffer at byte base WB_ (linear image == R6's)
#define WRITET(WB_) do {                                                   \
    const unsigned wa_ = wA + (WB_), wb2_ = wB + (WB_);                    \
    DSW(wa_, 0, ra0);     DSW(wa_, 8192, ra1);                             \
    DSW(wa_, 16384, ra2); DSW(wa_, 24576, ra3);                            \
    DSW(wb2_, 0, rb0);     DSW(wb2_, 8192, rb1);                           \
    DSW(wb2_, 16384, rb2); DSW(wb2_, 24576, rb3);                          \
} while (0)

// C[m][n] = sum_k A[m][k]*B[n][k].  perm as R6 (1 -> x=batch: XCD owns batch).
// EPI 0: store bf16.  EPI 1: scores epilogue.  EPI 2: store f32 = acc/aux1[row].
template <int EPI>
__global__ __launch_bounds__(512, 2) void gemm256(
    const unsigned short* __restrict__ A, int lda, long long sA,
    const unsigned short* __restrict__ B, int ldb, long long sB,
    void* __restrict__ Cv, int ldc, long long sC,
    int Kd, int perm,
    const float* __restrict__ aux1, int sAux1,
    const float* __restrict__ aux2, int sAux2,
    float invs) {
    __shared__ __attribute__((aligned(128))) unsigned short As[2 * 256 * 64];
    __shared__ __attribute__((aligned(128))) unsigned short Bs[2 * 256 * 64];

    const int z = perm ? blockIdx.x : blockIdx.z;
    const int jb = perm ? blockIdx.y : blockIdx.x;
    const int ib = perm ? blockIdx.z : blockIdx.y;
    const unsigned short* __restrict__ Ab = A + (size_t)z * sA;
    const unsigned short* __restrict__ Bb = B + (size_t)z * sB;
    const int i0 = ib * 256;
    const int j0 = jb * 256;
    const int tid = threadIdx.x;
    const int w = tid >> 6, lane = tid & 63;
    const int wr = w >> 2, wc = w & 3;          // 2 x 4 wave grid
    const int c16 = lane & 15, kq = lane >> 4;  // frag col / k-octet

    // staging source (pre-swizzled global chunk; LDS image linear == R6)
    const int lr0 = tid >> 3;                    // 0..63
    const int clog0 = (tid & 7) ^ (lr0 & 7);     // logical 16B chunk (involution)
    const unsigned short* pa = Ab + (size_t)(i0 + lr0) * lda + clog0 * 8;
    const unsigned short* pb = Bb + (size_t)(j0 + lr0) * ldb + clog0 * 8;
    const size_t lda64 = (size_t)64 * lda, ldb64 = (size_t)64 * ldb;

    // LDS write bases (bytes): thread chunk tid -> row lr0, stored chunk tid&7;
    // +8192 bytes per 64-row group.  tid*16 = lr0*128 + (tid&7)*16.
    const unsigned wA = lds_off(As) + (unsigned)tid * 16;
    const unsigned wB = lds_off(Bs) + (unsigned)tid * 16;

    // frag read bases (R6-verified): stored chunk = (kk*4+kq)^(row&7); row&7==c16&7
    const int swc = (kq ^ (c16 & 7)) << 4;
    const unsigned adrA0 = lds_off(As) + (unsigned)(wr * 128 + c16) * 128 + swc;
    const unsigned adrA0x = adrA0 ^ 64u;
    const unsigned adrB0 = lds_off(Bs) + (unsigned)(wc * 64 + c16) * 128 + swc;
    const unsigned adrB0x = adrB0 ^ 64u;

    f32x4 acc[8][4];
    const f32x4 zero = {0.f, 0.f, 0.f, 0.f};
#pragma unroll
    for (int i = 0; i < 8; ++i)
#pragma unroll
        for (int j = 0; j < 4; ++j) acc[i][j] = zero;

    u32x4 ra0, ra1, ra2, ra3, rb0, rb1, rb2, rb3;  // stage regs (one tile)
    bf16x8 aL[4][2], aH[4][2], bF[4][2];

    const int nt = Kd >> 6;  // BK=64 tiles; requires Kd % 64 == 0, nt >= 2

    // prologue: t0 -> regs -> buf0; t1 -> regs (stays in flight across barrier)
    LOADT(0);
    VMC0;
    WRITET(0u);
    LOADT(1);
    LGKM(0);
    wg_barrier();

    for (int t = 0; t < nt; ++t) {
        const unsigned rb_ = (t & 1) ? 32768u : 0u;   // read buf byte base
        const unsigned wb_ = (t & 1) ? 0u : 32768u;   // write buf (tile t+1)
        const unsigned aA = adrA0 + rb_, aAx = adrA0x + rb_;
        const unsigned aB = adrB0 + rb_, aBx = adrB0x + rb_;
        // (1) 16 reads: A rows wr*128+{0..63} (mi 0..3) + all B
        DSR(aL[0][0], aA, 0);    DSR(aL[0][1], aAx, 0);
        DSR(aL[1][0], aA, 2048); DSR(aL[1][1], aAx, 2048);
        DSR(aL[2][0], aA, 4096); DSR(aL[2][1], aAx, 4096);
        DSR(aL[3][0], aA, 6144); DSR(aL[3][1], aAx, 6144);
        DSR(bF[0][0], aB, 0);    DSR(bF[0][1], aBx, 0);
        DSR(bF[1][0], aB, 2048); DSR(bF[1][1], aBx, 2048);
        DSR(bF[2][0], aB, 4096); DSR(bF[2][1], aBx, 4096);
        DSR(bF[3][0], aB, 6144); DSR(bF[3][1], aBx, 6144);
        // (2) stage tile t+1 into other buf; issue loads for t+2
        if (t + 1 < nt) {
            VMC0;            // t+1 loads were issued a full tile ago
            WRITET(wb_);
            if (t + 2 < nt) LOADT(t + 2);
            LGKM(8);         // 16 reads + 8 writes outstanding -> reads done
        } else {
            LGKM(0);
        }
        SB0;
        __builtin_amdgcn_s_setprio(1);
#pragma unroll
        for (int kk = 0; kk < 2; ++kk)
#pragma unroll
            for (int mi = 0; mi < 4; ++mi)
#pragma unroll
                for (int ni = 0; ni < 4; ++ni)
                    MF(aL[mi][kk], bF[ni][kk], acc[mi][ni]);
        __builtin_amdgcn_s_setprio(0);
        // (4) A rows wr*128+{64..127} (mi 4..7)
        DSR(aH[0][0], aA, 8192);  DSR(aH[0][1], aAx, 8192);
        DSR(aH[1][0], aA, 10240); DSR(aH[1][1], aAx, 10240);
        DSR(aH[2][0], aA, 12288); DSR(aH[2][1], aAx, 12288);
        DSR(aH[3][0], aA, 14336); DSR(aH[3][1], aAx, 14336);
        LGKM(0); SB0;            // also retires the 8 ds_writes (long done)
        __builtin_amdgcn_s_setprio(1);
#pragma unroll
        for (int kk = 0; kk < 2; ++kk)
#pragma unroll
            for (int mi = 0; mi < 4; ++mi)
#pragma unroll
                for (int ni = 0; ni < 4; ++ni)
                    MF(aH[mi][kk], bF[ni][kk], acc[4 + mi][ni]);
        __builtin_amdgcn_s_setprio(0);
        // (5) single barrier per tile: publishes buf(t+1) writes
        wg_barrier();
    }

    // C/D layout: col = lane&15, row = (lane>>4)*4 + reg
    const int r4 = kq * 4;
    if constexpr (EPI == 0) {
        unsigned short* C = (unsigned short*)Cv + (size_t)z * sC;
#pragma unroll
        for (int mi = 0; mi < 8; ++mi)
#pragma unroll
            for (int ni = 0; ni < 4; ++ni) {
                const int row = i0 + wr * 128 + mi * 16 + r4;
                const int col = j0 + wc * 64 + ni * 16 + c16;
#pragma unroll
                for (int r = 0; r < 4; ++r)
                    C[(size_t)(row + r) * ldc + col] = f2b(acc[mi][ni][r]);
            }
    } else if constexpr (EPI == 1) {
        unsigned short* C = (unsigned short*)Cv + (size_t)z * sC;
        const float* q2b = aux1 + (size_t)z * sAux1;
        const float* k2b = aux2 + (size_t)z * sAux2;
#pragma unroll
        for (int mi = 0; mi < 8; ++mi)
#pragma unroll
            for (int ni = 0; ni < 4; ++ni) {
                const int row = i0 + wr * 128 + mi * 16 + r4;
                const int col = j0 + wc * 64 + ni * 16 + c16;
                const float k2v = k2b[col];
#pragma unroll
                for (int r = 0; r < 4; ++r) {
                    float d2 = q2b[row + r] + k2v - 2.0f * acc[mi][ni][r];
                    float e = __expf(sqrtf(fmaxf(d2, 0.f)) * invs);
                    C[(size_t)(row + r) * ldc + col] = f2b(e);
                }
            }
    } else {
        float* C = (float*)Cv + (size_t)z * sC;
        const float* lb = aux1 + (size_t)z * sAux1;
#pragma unroll
        for (int mi = 0; mi < 8; ++mi)
#pragma unroll
            for (int ni = 0; ni < 4; ++ni) {
                const int row = i0 + wr * 128 + mi * 16 + r4;
                const int col = j0 + wc * 64 + ni * 16 + c16;
#pragma unroll
                for (int r = 0; r < 4; ++r)
                    C[(size_t)(row + r) * ldc + col] = acc[mi][ni][r] / lb[row + r];
            }
    }
}

extern "C" void kernel_launch(void* const* d_in, const int* in_sizes, int n_in,
                              void* d_out, int out_size, void* d_ws, size_t ws_size,
                              hipStream_t stream) {
    const float* x = (const float*)d_in[0];
    const float* Wq = (const float*)d_in[1];
    const float* Wk = (const float*)d_in[2];
    const float* Wv = (const float*)d_in[3];
    const int Bz = 8, S = 2048, D = 768, F = 768;
    const int BS = Bz * S;  // 16384

    const size_t szX = (size_t)BS * D * 2;
    const size_t szW = (size_t)F * D * 2;
    const size_t szE = (size_t)Bz * S * S * 2;

    char* p = (char*)d_ws;
    unsigned short* xb = (unsigned short*)p;  p += szX;
    unsigned short* Wqb = (unsigned short*)p; p += szW;
    unsigned short* Wkb = (unsigned short*)p; p += szW;
    unsigned short* Wvb = (unsigned short*)p; p += szW;
    unsigned short* Qm = (unsigned short*)p;  p += szX;
    unsigned short* Km = (unsigned short*)p;  p += szX;
    unsigned short* VT = (unsigned short*)p;  p += szX;  // [F][BS]
    unsigned short* E = (unsigned short*)p;   p += szE;  // [Bz][S][S]
    float* q2 = (float*)p;   p += (size_t)BS * 4;
    float* k2 = (float*)p;   p += (size_t)BS * 4;
    float* lsum = (float*)p; p += (size_t)BS * 4;
    if ((size_t)(p - (char*)d_ws) > ws_size) return;  // ~164 MiB scratch required

    const float invs = 1.0f / sqrtf(768.0f);

    // 1) casts
    castk<<<(BS * D / 4 + 255) / 256, 256, 0, stream>>>(x, xb, BS * D / 4);
    castk<<<(F * D / 4 + 255) / 256, 256, 0, stream>>>(Wq, Wqb, F * D / 4);
    castk<<<(F * D / 4 + 255) / 256, 256, 0, stream>>>(Wk, Wkb, F * D / 4);
    castk<<<(F * D / 4 + 255) / 256, 256, 0, stream>>>(Wv, Wvb, F * D / 4);

    // 2) Q,K = x . W^T  (z=0 -> Wq, z=1 -> Wk); W L2-resident, perm=0
    gemm256<0><<<dim3(F / 256, BS / 256, 2), 512, 0, stream>>>(
        xb, D, 0,
        Wqb, D, (long long)F * D,
        Qm, F, (long long)BS * F,
        D, 0, nullptr, 0, nullptr, 0, 0.f);

    //    V^T = Wv . x^T   -> VT[f][s]; perm=0
    gemm256<0><<<dim3(BS / 256, F / 256, 1), 512, 0, stream>>>(
        Wvb, D, 0,
        xb, D, 0,
        VT, BS, 0,
        D, 0, nullptr, 0, nullptr, 0, 0.f);

    // 3) row norms of Q,K
    rowreduce<1><<<BS / 4, 256, 0, stream>>>(Qm, F, BS, q2);
    rowreduce<1><<<BS / 4, 256, 0, stream>>>(Km, F, BS, k2);

    // 4) E = exp(sqrt(max(q2+k2-2*Q.K^T,0))*invs); perm=1: XCD i owns batch i
    gemm256<1><<<dim3(Bz, S / 256, S / 256), 512, 0, stream>>>(
        Qm, F, (long long)S * F,
        Km, F, (long long)S * F,
        E, S, (long long)S * S,
        F, 1, q2, S, k2, S, invs);

    // 5) l = rowsum(E)
    rowreduce<0><<<BS / 4, 256, 0, stream>>>(E, S, BS, lsum);

    // 6) out = (E . V) / l; perm=1: XCD i reads the E_z it just wrote
    gemm256<2><<<dim3(Bz, F / 256, S / 256), 512, 0, stream>>>(
        E, S, (long long)S * S,
        VT, BS, (long long)S,
        d_out, F, (long long)S * F,
        S, 1, lsum, S, nullptr, 0, 0.f);
}

// Round 11
// 246.023 us; speedup vs baseline: 1.3883x; 1.0328x over previous
//
#include <hip/hip_runtime.h>
#include <hip/hip_fp8.h>
#include <stdint.h>
#include <math.h>

// cdist-attention. R11: fp8-e4m3 SCORES path (byte-delivery theory).
// Evidence: R8 (no loads: ~1 PF) vs R6/R10 (DMA or reg-staged, prefetched:
// ~430 TF) -> global-load delivery ~10-15 B/cyc/CU is the wall, path- and
// hit-tier-independent. Lever: staged bytes. QK stores Q,K as e4m3 (EPI3);
// q2/k2 recomputed from fp8-rounded values (exact d2 consistency);
// gemm256f8 = R10's reg-staged single-barrier loop with 8B-slot XOR swizzle
// + ds_read_b64 frags + mfma_f32_16x16x32_fp8_fp8 -> E bf16. VT/PV/E bf16.

typedef __attribute__((ext_vector_type(8))) __bf16 bf16x8;
typedef __attribute__((ext_vector_type(4))) float f32x4;
typedef __attribute__((ext_vector_type(4))) unsigned int u32x4;
typedef __attribute__((ext_vector_type(2))) unsigned int u32x2;

__device__ __forceinline__ unsigned short f2b(float f) {
    unsigned u = __float_as_uint(f);
    unsigned r = 0x7fffu + ((u >> 16) & 1u);
    return (unsigned short)((u + r) >> 16);
}
__device__ __forceinline__ float b2f(unsigned short h) {
    return __uint_as_float(((unsigned)h) << 16);
}
__device__ __forceinline__ unsigned char f2f8(float f) {
    __hip_fp8_e4m3 t(f);
    return t.__x;
}
__device__ __forceinline__ float f8tof(unsigned char b) {
    int e = (b >> 3) & 15, m = b & 7;
    float v = e ? ldexpf(8.0f + m, e - 10) : ldexpf((float)m, -9);
    return (b & 0x80) ? -v : v;
}

__device__ __forceinline__ void wg_barrier() {
    asm volatile("" ::: "memory");
    __builtin_amdgcn_s_barrier();
    asm volatile("" ::: "memory");
}

__device__ __forceinline__ unsigned lds_off(const void* p) {
    return (unsigned)(uintptr_t)(const __attribute__((address_space(3))) char*)p;
}

__global__ __launch_bounds__(256) void castk(const float* __restrict__ src,
                                             unsigned short* __restrict__ dst, int n4) {
    int i = blockIdx.x * 256 + threadIdx.x;
    if (i >= n4) return;
    float4 v = ((const float4*)src)[i];
    ushort4 o;
    o.x = f2b(v.x); o.y = f2b(v.y); o.z = f2b(v.z); o.w = f2b(v.w);
    ((ushort4*)dst)[i] = o;
}

// MODE 0: row sum; MODE 1: row sum of squares. One wave per row (bf16 input).
template <int MODE>
__global__ __launch_bounds__(256) void rowreduce(const unsigned short* __restrict__ X,
                                                 int L, int rows, float* __restrict__ out) {
    int w = threadIdx.x >> 6, lane = threadIdx.x & 63;
    int row = blockIdx.x * 4 + w;
    if (row >= rows) return;
    const unsigned short* xr = X + (size_t)row * L;
    float s = 0.f;
    int passes = L >> 8;
    for (int p = 0; p < passes; ++p) {
        ushort4 u = *(const ushort4*)(xr + (p << 8) + lane * 4);
        float a = b2f(u.x), b = b2f(u.y), c = b2f(u.z), d = b2f(u.w);
        s += MODE ? (a * a + b * b + c * c + d * d) : (a + b + c + d);
    }
#pragma unroll
    for (int o = 32; o > 0; o >>= 1) s += __shfl_down(s, o);
    if (lane == 0) out[row] = s;
}

// row sum of squares over fp8-e4m3 rows (consistency with fp8 MFMA operands)
__global__ __launch_bounds__(256) void rowreduce8(const unsigned char* __restrict__ X,
                                                  int L, int rows, float* __restrict__ out) {
    int w = threadIdx.x >> 6, lane = threadIdx.x & 63;
    int row = blockIdx.x * 4 + w;
    if (row >= rows) return;
    const unsigned char* xr = X + (size_t)row * L;
    float s = 0.f;
    int passes = L >> 8;  // 256 B per pass (64 lanes x 4)
    for (int p = 0; p < passes; ++p) {
        uchar4 u = *(const uchar4*)(xr + (p << 8) + lane * 4);
        float a = f8tof(u.x), b = f8tof(u.y), c = f8tof(u.z), d = f8tof(u.w);
        s += a * a + b * b + c * c + d * d;
    }
#pragma unroll
    for (int o = 32; o > 0; o >>= 1) s += __shfl_down(s, o);
    if (lane == 0) out[row] = s;
}

#define MF(A_, B_, C_) (C_) = __builtin_amdgcn_mfma_f32_16x16x32_bf16((A_), (B_), (C_), 0, 0, 0)
#define MF8(A_, B_, C_) (C_) = __builtin_amdgcn_mfma_f32_16x16x32_fp8_fp8((A_), (B_), (C_), 0, 0, 0)
#define DSR(dst_, a_, imm_) \
    asm volatile("ds_read_b128 %0, %1 offset:" #imm_ : "=v"(dst_) : "v"(a_))
#define DSR64(dst_, a_, imm_) \
    asm volatile("ds_read_b64 %0, %1 offset:" #imm_ : "=v"(dst_) : "v"(a_))
#define GL4(d_, p_) asm volatile("global_load_dwordx4 %0, %1, off" : "=v"(d_) : "v"(p_))
#define GL2(d_, p_) asm volatile("global_load_dwordx2 %0, %1, off" : "=v"(d_) : "v"(p_))
#define DSW(a_, imm_, d_) \
    asm volatile("ds_write_b128 %0, %1 offset:" #imm_ :: "v"(a_), "v"(d_) : "memory")
#define DSW64(a_, imm_, d_) \
    asm volatile("ds_write_b64 %0, %1 offset:" #imm_ :: "v"(a_), "v"(d_) : "memory")
#define LGKM(n_) asm volatile("s_waitcnt lgkmcnt(" #n_ ")" ::: "memory")
#define VMC0 asm volatile("s_waitcnt vmcnt(0)" ::: "memory")
#define SB0 __builtin_amdgcn_sched_barrier(0)

// ---------------- bf16 reg-staged GEMM (R10, verified) ----------------
#define LOADT(T_) do {                                                     \
    const size_t ko_ = (size_t)(T_) * 64;                                  \
    GL4(ra0, pa + ko_);             GL4(ra1, pa + lda64 + ko_);            \
    GL4(ra2, pa + 2 * lda64 + ko_); GL4(ra3, pa + 3 * lda64 + ko_);        \
    GL4(rb0, pb + ko_);             GL4(rb1, pb + ldb64 + ko_);            \
    GL4(rb2, pb + 2 * ldb64 + ko_); GL4(rb3, pb + 3 * ldb64 + ko_);        \
} while (0)
#define WRITET(WB_) do {                                                   \
    const unsigned wa_ = wA + (WB_), wb2_ = wB + (WB_);                    \
    DSW(wa_, 0, ra0);     DSW(wa_, 8192, ra1);                             \
    DSW(wa_, 16384, ra2); DSW(wa_, 24576, ra3);                            \
    DSW(wb2_, 0, rb0);     DSW(wb2_, 8192, rb1);                           \
    DSW(wb2_, 16384, rb2); DSW(wb2_, 24576, rb3);                          \
} while (0)

// EPI 0: bf16 out. EPI 2: f32 = acc/aux1[row]. EPI 3: fp8-e4m3 out.
template <int EPI>
__global__ __launch_bounds__(512, 2) void gemm256(
    const unsigned short* __restrict__ A, int lda, long long sA,
    const unsigned short* __restrict__ B, int ldb, long long sB,
    void* __restrict__ Cv, int ldc, long long sC,
    int Kd, int perm,
    const float* __restrict__ aux1, int sAux1) {
    __shared__ __attribute__((aligned(128))) unsigned short As[2 * 256 * 64];
    __shared__ __attribute__((aligned(128))) unsigned short Bs[2 * 256 * 64];

    const int z = perm ? blockIdx.x : blockIdx.z;
    const int jb = perm ? blockIdx.y : blockIdx.x;
    const int ib = perm ? blockIdx.z : blockIdx.y;
    const unsigned short* __restrict__ Ab = A + (size_t)z * sA;
    const unsigned short* __restrict__ Bb = B + (size_t)z * sB;
    const int i0 = ib * 256, j0 = jb * 256;
    const int tid = threadIdx.x;
    const int w = tid >> 6, lane = tid & 63;
    const int wr = w >> 2, wc = w & 3;
    const int c16 = lane & 15, kq = lane >> 4;

    const int lr0 = tid >> 3;
    const int clog0 = (tid & 7) ^ (lr0 & 7);
    const unsigned short* pa = Ab + (size_t)(i0 + lr0) * lda + clog0 * 8;
    const unsigned short* pb = Bb + (size_t)(j0 + lr0) * ldb + clog0 * 8;
    const size_t lda64 = (size_t)64 * lda, ldb64 = (size_t)64 * ldb;

    const unsigned wA = lds_off(As) + (unsigned)tid * 16;
    const unsigned wB = lds_off(Bs) + (unsigned)tid * 16;

    const int swc = (kq ^ (c16 & 7)) << 4;
    const unsigned adrA0 = lds_off(As) + (unsigned)(wr * 128 + c16) * 128 + swc;
    const unsigned adrA0x = adrA0 ^ 64u;
    const unsigned adrB0 = lds_off(Bs) + (unsigned)(wc * 64 + c16) * 128 + swc;
    const unsigned adrB0x = adrB0 ^ 64u;

    f32x4 acc[8][4];
    const f32x4 zero = {0.f, 0.f, 0.f, 0.f};
#pragma unroll
    for (int i = 0; i < 8; ++i)
#pragma unroll
        for (int j = 0; j < 4; ++j) acc[i][j] = zero;

    u32x4 ra0, ra1, ra2, ra3, rb0, rb1, rb2, rb3;
    bf16x8 aL[4][2], aH[4][2], bF[4][2];

    const int nt = Kd >> 6;

    LOADT(0);
    VMC0;
    WRITET(0u);
    LOADT(1);
    LGKM(0);
    wg_barrier();

    for (int t = 0; t < nt; ++t) {
        const unsigned rb_ = (t & 1) ? 32768u : 0u;
        const unsigned wb_ = (t & 1) ? 0u : 32768u;
        const unsigned aA = adrA0 + rb_, aAx = adrA0x + rb_;
        const unsigned aB = adrB0 + rb_, aBx = adrB0x + rb_;
        DSR(aL[0][0], aA, 0);    DSR(aL[0][1], aAx, 0);
        DSR(aL[1][0], aA, 2048); DSR(aL[1][1], aAx, 2048);
        DSR(aL[2][0], aA, 4096); DSR(aL[2][1], aAx, 4096);
        DSR(aL[3][0], aA, 6144); DSR(aL[3][1], aAx, 6144);
        DSR(bF[0][0], aB, 0);    DSR(bF[0][1], aBx, 0);
        DSR(bF[1][0], aB, 2048); DSR(bF[1][1], aBx, 2048);
        DSR(bF[2][0], aB, 4096); DSR(bF[2][1], aBx, 4096);
        DSR(bF[3][0], aB, 6144); DSR(bF[3][1], aBx, 6144);
        if (t + 1 < nt) {
            VMC0;
            WRITET(wb_);
            if (t + 2 < nt) LOADT(t + 2);
            LGKM(8);
        } else {
            LGKM(0);
        }
        SB0;
        __builtin_amdgcn_s_setprio(1);
#pragma unroll
        for (int kk = 0; kk < 2; ++kk)
#pragma unroll
            for (int mi = 0; mi < 4; ++mi)
#pragma unroll
                for (int ni = 0; ni < 4; ++ni)
                    MF(aL[mi][kk], bF[ni][kk], acc[mi][ni]);
        __builtin_amdgcn_s_setprio(0);
        DSR(aH[0][0], aA, 8192);  DSR(aH[0][1], aAx, 8192);
        DSR(aH[1][0], aA, 10240); DSR(aH[1][1], aAx, 10240);
        DSR(aH[2][0], aA, 12288); DSR(aH[2][1], aAx, 12288);
        DSR(aH[3][0], aA, 14336); DSR(aH[3][1], aAx, 14336);
        LGKM(0); SB0;
        __builtin_amdgcn_s_setprio(1);
#pragma unroll
        for (int kk = 0; kk < 2; ++kk)
#pragma unroll
            for (int mi = 0; mi < 4; ++mi)
#pragma unroll
                for (int ni = 0; ni < 4; ++ni)
                    MF(aH[mi][kk], bF[ni][kk], acc[4 + mi][ni]);
        __builtin_amdgcn_s_setprio(0);
        wg_barrier();
    }

    const int r4 = kq * 4;
    if constexpr (EPI == 0) {
        unsigned short* C = (unsigned short*)Cv + (size_t)z * sC;
#pragma unroll
        for (int mi = 0; mi < 8; ++mi)
#pragma unroll
            for (int ni = 0; ni < 4; ++ni) {
                const int row = i0 + wr * 128 + mi * 16 + r4;
                const int col = j0 + wc * 64 + ni * 16 + c16;
#pragma unroll
                for (int r = 0; r < 4; ++r)
                    C[(size_t)(row + r) * ldc + col] = f2b(acc[mi][ni][r]);
            }
    } else if constexpr (EPI == 3) {
        unsigned char* C = (unsigned char*)Cv + (size_t)z * sC;
#pragma unroll
        for (int mi = 0; mi < 8; ++mi)
#pragma unroll
            for (int ni = 0; ni < 4; ++ni) {
                const int row = i0 + wr * 128 + mi * 16 + r4;
                const int col = j0 + wc * 64 + ni * 16 + c16;
#pragma unroll
                for (int r = 0; r < 4; ++r)
                    C[(size_t)(row + r) * ldc + col] = f2f8(acc[mi][ni][r]);
            }
    } else {
        float* C = (float*)Cv + (size_t)z * sC;
        const float* lb = aux1 + (size_t)z * sAux1;
#pragma unroll
        for (int mi = 0; mi < 8; ++mi)
#pragma unroll
            for (int ni = 0; ni < 4; ++ni) {
                const int row = i0 + wr * 128 + mi * 16 + r4;
                const int col = j0 + wc * 64 + ni * 16 + c16;
#pragma unroll
                for (int r = 0; r < 4; ++r)
                    C[(size_t)(row + r) * ldc + col] = acc[mi][ni][r] / lb[row + r];
            }
    }
}

// ---------------- fp8 scores GEMM (reg-staged, 8B-slot swizzle) ----------------
// LDS: [2 buf][256 rows][64 B]; slot s(8B) stored = logical ^ (row&7).
// Verified by element trace: A[17][13] staged by tid136 -> byte 1088; read by
// (c16=1,kq=1,mi=1) at (1*64 + ((1^1)<<3)) + 1024 = 1088. kk=1 slot = base^4
// -> addr^32 (m-independent).
#define LOADT8(T_) do {                                                    \
    const size_t ko_ = (size_t)(T_) * 64;                                  \
    GL2(fa0, pa8 + ko_);              GL2(fa1, pa8 + lda64b + ko_);        \
    GL2(fa2, pa8 + 2 * lda64b + ko_); GL2(fa3, pa8 + 3 * lda64b + ko_);    \
    GL2(fb0, pb8 + ko_);              GL2(fb1, pb8 + ldb64b + ko_);        \
    GL2(fb2, pb8 + 2 * ldb64b + ko_); GL2(fb3, pb8 + 3 * ldb64b + ko_);    \
} while (0)
#define WRITET8(WB_) do {                                                  \
    const unsigned wa_ = wA8 + (WB_), wb2_ = wB8 + (WB_);                  \
    DSW64(wa_, 0, fa0);     DSW64(wa_, 4096, fa1);                         \
    DSW64(wa_, 8192, fa2);  DSW64(wa_, 12288, fa3);                        \
    DSW64(wb2_, 0, fb0);    DSW64(wb2_, 4096, fb1);                        \
    DSW64(wb2_, 8192, fb2); DSW64(wb2_, 12288, fb3);                       \
} while (0)

__global__ __launch_bounds__(512, 2) void gemm256f8(
    const unsigned char* __restrict__ A, int lda, long long sA,
    const unsigned char* __restrict__ B, int ldb, long long sB,
    unsigned short* __restrict__ Cq, int ldc, long long sC,
    int Kd,
    const float* __restrict__ q2a, int sQ2,
    const float* __restrict__ k2a, int sK2,
    float invs) {
    __shared__ __attribute__((aligned(128))) unsigned char As8[2 * 256 * 64];
    __shared__ __attribute__((aligned(128))) unsigned char Bs8[2 * 256 * 64];

    const int z = blockIdx.x;        // perm=1: XCD i owns batch i
    const int jb = blockIdx.y, ib = blockIdx.z;
    const unsigned char* __restrict__ Ab = A + (size_t)z * sA;
    const unsigned char* __restrict__ Bb = B + (size_t)z * sB;
    const int i0 = ib * 256, j0 = jb * 256;
    const int tid = threadIdx.x;
    const int w = tid >> 6, lane = tid & 63;
    const int wr = w >> 2, wc = w & 3;
    const int c16 = lane & 15, kq = lane >> 4;

    // staging: thread tid covers rows lr0+{0,64,128,192}, stored slot tid&7,
    // logical slot (tid&7)^(lr0&7) (same for all 4 rows since +64 keeps &7)
    const int lr0 = tid >> 3;
    const int slog = (tid & 7) ^ (lr0 & 7);
    const unsigned char* pa8 = Ab + (size_t)(i0 + lr0) * lda + slog * 8;
    const unsigned char* pb8 = Bb + (size_t)(j0 + lr0) * ldb + slog * 8;
    const size_t lda64b = (size_t)64 * lda, ldb64b = (size_t)64 * ldb;

    const unsigned wA8 = lds_off(As8) + (unsigned)tid * 8;
    const unsigned wB8 = lds_off(Bs8) + (unsigned)tid * 8;

    // frag read: row*64 + ((kq ^ (c16&7))<<3); kk=1 -> ^32; mi/ni -> +1024 imm
    const int sw8 = (kq ^ (c16 & 7)) << 3;
    const unsigned adrA0 = lds_off(As8) + (unsigned)(wr * 128 + c16) * 64 + sw8;
    const unsigned adrA0x = adrA0 ^ 32u;
    const unsigned adrB0 = lds_off(Bs8) + (unsigned)(wc * 64 + c16) * 64 + sw8;
    const unsigned adrB0x = adrB0 ^ 32u;

    f32x4 acc[8][4];
    const f32x4 zero = {0.f, 0.f, 0.f, 0.f};
#pragma unroll
    for (int i = 0; i < 8; ++i)
#pragma unroll
        for (int j = 0; j < 4; ++j) acc[i][j] = zero;

    u32x2 fa0, fa1, fa2, fa3, fb0, fb1, fb2, fb3;
    long aL[4][2], aH[4][2], bF[4][2];

    const int nt = Kd >> 6;  // BK=64

    LOADT8(0);
    VMC0;
    WRITET8(0u);
    LOADT8(1);
    LGKM(0);
    wg_barrier();

    for (int t = 0; t < nt; ++t) {
        const unsigned rb_ = (t & 1) ? 16384u : 0u;
        const unsigned wb_ = (t & 1) ? 0u : 16384u;
        const unsigned aA = adrA0 + rb_, aAx = adrA0x + rb_;
        const unsigned aB = adrB0 + rb_, aBx = adrB0x + rb_;
        DSR64(aL[0][0], aA, 0);    DSR64(aL[0][1], aAx, 0);
        DSR64(aL[1][0], aA, 1024); DSR64(aL[1][1], aAx, 1024);
        DSR64(aL[2][0], aA, 2048); DSR64(aL[2][1], aAx, 2048);
        DSR64(aL[3][0], aA, 3072); DSR64(aL[3][1], aAx, 3072);
        DSR64(bF[0][0], aB, 0);    DSR64(bF[0][1], aBx, 0);
        DSR64(bF[1][0], aB, 1024); DSR64(bF[1][1], aBx, 1024);
        DSR64(bF[2][0], aB, 2048); DSR64(bF[2][1], aBx, 2048);
        DSR64(bF[3][0], aB, 3072); DSR64(bF[3][1], aBx, 3072);
        if (t + 1 < nt) {
            VMC0;
            WRITET8(wb_);
            if (t + 2 < nt) LOADT8(t + 2);
            LGKM(8);
        } else {
            LGKM(0);
        }
        SB0;
        __builtin_amdgcn_s_setprio(1);
#pragma unroll
        for (int kk = 0; kk < 2; ++kk)
#pragma unroll
            for (int mi = 0; mi < 4; ++mi)
#pragma unroll
                for (int ni = 0; ni < 4; ++ni)
                    MF8(aL[mi][kk], bF[ni][kk], acc[mi][ni]);
        __builtin_amdgcn_s_setprio(0);
        DSR64(aH[0][0], aA, 4096); DSR64(aH[0][1], aAx, 4096);
        DSR64(aH[1][0], aA, 5120); DSR64(aH[1][1], aAx, 5120);
        DSR64(aH[2][0], aA, 6144); DSR64(aH[2][1], aAx, 6144);
        DSR64(aH[3][0], aA, 7168); DSR64(aH[3][1], aAx, 7168);
        LGKM(0); SB0;
        __builtin_amdgcn_s_setprio(1);
#pragma unroll
        for (int kk = 0; kk < 2; ++kk)
#pragma unroll
            for (int mi = 0; mi < 4; ++mi)
#pragma unroll
                for (int ni = 0; ni < 4; ++ni)
                    MF8(aH[mi][kk], bF[ni][kk], acc[4 + mi][ni]);
        __builtin_amdgcn_s_setprio(0);
        wg_barrier();
    }

    // scores epilogue: E = exp(sqrt(max(q2+k2-2*acc,0))*invs) as bf16
    const int r4 = kq * 4;
    unsigned short* C = Cq + (size_t)z * sC;
    const float* q2b = q2a + (size_t)z * sQ2;
    const float* k2b = k2a + (size_t)z * sK2;
#pragma unroll
    for (int mi = 0; mi < 8; ++mi)
#pragma unroll
        for (int ni = 0; ni < 4; ++ni) {
            const int row = i0 + wr * 128 + mi * 16 + r4;
            const int col = j0 + wc * 64 + ni * 16 + c16;
            const float k2v = k2b[col];
#pragma unroll
            for (int r = 0; r < 4; ++r) {
                float d2 = q2b[row + r] + k2v - 2.0f * acc[mi][ni][r];
                float e = __expf(sqrtf(fmaxf(d2, 0.f)) * invs);
                C[(size_t)(row + r) * ldc + col] = f2b(e);
            }
        }
}

extern "C" void kernel_launch(void* const* d_in, const int* in_sizes, int n_in,
                              void* d_out, int out_size, void* d_ws, size_t ws_size,
                              hipStream_t stream) {
    const float* x = (const float*)d_in[0];
    const float* Wq = (const float*)d_in[1];
    const float* Wk = (const float*)d_in[2];
    const float* Wv = (const float*)d_in[3];
    const int Bz = 8, S = 2048, D = 768, F = 768;
    const int BS = Bz * S;  // 16384

    const size_t szX = (size_t)BS * D * 2;
    const size_t szW = (size_t)F * D * 2;
    const size_t szQ8 = (size_t)BS * F;      // fp8
    const size_t szE = (size_t)Bz * S * S * 2;

    char* p = (char*)d_ws;
    unsigned short* xb = (unsigned short*)p;  p += szX;
    unsigned short* Wqb = (unsigned short*)p; p += szW;
    unsigned short* Wkb = (unsigned short*)p; p += szW;
    unsigned short* Wvb = (unsigned short*)p; p += szW;
    unsigned char* Q8 = (unsigned char*)p;    p += szQ8;  // Q8/K8 contiguous
    unsigned char* K8 = (unsigned char*)p;    p += szQ8;
    unsigned short* VT = (unsigned short*)p;  p += szX;   // [F][BS]
    unsigned short* E = (unsigned short*)p;   p += szE;   // [Bz][S][S]
    float* q2 = (float*)p;   p += (size_t)BS * 4;
    float* k2 = (float*)p;   p += (size_t)BS * 4;
    float* lsum = (float*)p; p += (size_t)BS * 4;
    if ((size_t)(p - (char*)d_ws) > ws_size) return;  // ~147 MiB scratch required

    const float invs = 1.0f / sqrtf(768.0f);

    // 1) casts
    castk<<<(BS * D / 4 + 255) / 256, 256, 0, stream>>>(x, xb, BS * D / 4);
    castk<<<(F * D / 4 + 255) / 256, 256, 0, stream>>>(Wq, Wqb, F * D / 4);
    castk<<<(F * D / 4 + 255) / 256, 256, 0, stream>>>(Wk, Wkb, F * D / 4);
    castk<<<(F * D / 4 + 255) / 256, 256, 0, stream>>>(Wv, Wvb, F * D / 4);

    // 2) Q8,K8 = e4m3(x . W^T)  (z=0 -> Wq->Q8, z=1 -> Wk->K8)
    gemm256<3><<<dim3(F / 256, BS / 256, 2), 512, 0, stream>>>(
        xb, D, 0,
        Wqb, D, (long long)F * D,
        Q8, F, (long long)BS * F,
        D, 0, nullptr, 0);

    //    V^T = Wv . x^T   -> VT[f][s] (bf16)
    gemm256<0><<<dim3(BS / 256, F / 256, 1), 512, 0, stream>>>(
        Wvb, D, 0,
        xb, D, 0,
        VT, BS, 0,
        D, 0, nullptr, 0);

    // 3) q2,k2 from the fp8-rounded values (exact consistency with fp8 MFMA)
    rowreduce8<<<BS / 4, 256, 0, stream>>>(Q8, F, BS, q2);
    rowreduce8<<<BS / 4, 256, 0, stream>>>(K8, F, BS, k2);

    // 4) E = exp(sqrt(max(q2+k2-2*Q8.K8^T,0))*invs); x=batch -> XCD-pinned
    gemm256f8<<<dim3(Bz, S / 256, S / 256), 512, 0, stream>>>(
        Q8, F, (long long)S * F,
        K8, F, (long long)S * F,
        E, S, (long long)S * S,
        F, q2, S, k2, S, invs);

    // 5) l = rowsum(E)
    rowreduce<0><<<BS / 4, 256, 0, stream>>>(E, S, BS, lsum);

    // 6) out = (E . V) / l; x=batch -> XCD reads the E_z it just wrote
    gemm256<2><<<dim3(Bz, F / 256, S / 256), 512, 0, stream>>>(
        E, S, (long long)S * S,
        VT, BS, (long long)S,
        d_out, F, (long long)S * F,
        S, 1, lsum, S);
}

// Round 12
// 244.869 us; speedup vs baseline: 1.3948x; 1.0047x over previous
//
#include <hip/hip_runtime.h>
#include <hip/hip_fp8.h>
#include <stdint.h>
#include <math.h>

// cdist-attention. R12 = R11 + COALESCED EPILOGUES (per-wave LDS transpose).
// Evidence: every scores variant R1-R11 ran ~112-140us with identical
// scattered-narrow-store epilogues (128 x 2B stores/thread; QK fp8: 1B!).
// R8 probe decomposition: K-loop alone ~20us/pass (~MFMA ceiling), epilogue
// ~55us. Fix: after K-loop (LDS dead), each wave transposes its 16x64 subtile
// per mi through a private LDS region and stores full 16B-aligned dwordx4
// lines. K-loops/staging/swizzles/XCD perms byte-identical to R11.

typedef __attribute__((ext_vector_type(8))) __bf16 bf16x8;
typedef __attribute__((ext_vector_type(4))) float f32x4;
typedef __attribute__((ext_vector_type(4))) unsigned int u32x4;
typedef __attribute__((ext_vector_type(2))) unsigned int u32x2;

__device__ __forceinline__ unsigned short f2b(float f) {
    unsigned u = __float_as_uint(f);
    unsigned r = 0x7fffu + ((u >> 16) & 1u);
    return (unsigned short)((u + r) >> 16);
}
__device__ __forceinline__ float b2f(unsigned short h) {
    return __uint_as_float(((unsigned)h) << 16);
}
__device__ __forceinline__ unsigned char f2f8(float f) {
    __hip_fp8_e4m3 t(f);
    return t.__x;
}
__device__ __forceinline__ float f8tof(unsigned char b) {
    int e = (b >> 3) & 15, m = b & 7;
    float v = e ? ldexpf(8.0f + m, e - 10) : ldexpf((float)m, -9);
    return (b & 0x80) ? -v : v;
}

__device__ __forceinline__ void wg_barrier() {
    asm volatile("" ::: "memory");
    __builtin_amdgcn_s_barrier();
    asm volatile("" ::: "memory");
}

__device__ __forceinline__ unsigned lds_off(const void* p) {
    return (unsigned)(uintptr_t)(const __attribute__((address_space(3))) char*)p;
}

__global__ __launch_bounds__(256) void castk(const float* __restrict__ src,
                                             unsigned short* __restrict__ dst, int n4) {
    int i = blockIdx.x * 256 + threadIdx.x;
    if (i >= n4) return;
    float4 v = ((const float4*)src)[i];
    ushort4 o;
    o.x = f2b(v.x); o.y = f2b(v.y); o.z = f2b(v.z); o.w = f2b(v.w);
    ((ushort4*)dst)[i] = o;
}

// MODE 0: row sum; MODE 1: row sum of squares. One wave per row (bf16 input).
template <int MODE>
__global__ __launch_bounds__(256) void rowreduce(const unsigned short* __restrict__ X,
                                                 int L, int rows, float* __restrict__ out) {
    int w = threadIdx.x >> 6, lane = threadIdx.x & 63;
    int row = blockIdx.x * 4 + w;
    if (row >= rows) return;
    const unsigned short* xr = X + (size_t)row * L;
    float s = 0.f;
    int passes = L >> 8;
    for (int p = 0; p < passes; ++p) {
        ushort4 u = *(const ushort4*)(xr + (p << 8) + lane * 4);
        float a = b2f(u.x), b = b2f(u.y), c = b2f(u.z), d = b2f(u.w);
        s += MODE ? (a * a + b * b + c * c + d * d) : (a + b + c + d);
    }
#pragma unroll
    for (int o = 32; o > 0; o >>= 1) s += __shfl_down(s, o);
    if (lane == 0) out[row] = s;
}

// row sum of squares over fp8-e4m3 rows (consistency with fp8 MFMA operands)
__global__ __launch_bounds__(256) void rowreduce8(const unsigned char* __restrict__ X,
                                                  int L, int rows, float* __restrict__ out) {
    int w = threadIdx.x >> 6, lane = threadIdx.x & 63;
    int row = blockIdx.x * 4 + w;
    if (row >= rows) return;
    const unsigned char* xr = X + (size_t)row * L;
    float s = 0.f;
    int passes = L >> 8;
    for (int p = 0; p < passes; ++p) {
        uchar4 u = *(const uchar4*)(xr + (p << 8) + lane * 4);
        float a = f8tof(u.x), b = f8tof(u.y), c = f8tof(u.z), d = f8tof(u.w);
        s += a * a + b * b + c * c + d * d;
    }
#pragma unroll
    for (int o = 32; o > 0; o >>= 1) s += __shfl_down(s, o);
    if (lane == 0) out[row] = s;
}

#define MF(A_, B_, C_) (C_) = __builtin_amdgcn_mfma_f32_16x16x32_bf16((A_), (B_), (C_), 0, 0, 0)
#define MF8(A_, B_, C_) (C_) = __builtin_amdgcn_mfma_f32_16x16x32_fp8_fp8((A_), (B_), (C_), 0, 0, 0)
#define DSR(dst_, a_, imm_) \
    asm volatile("ds_read_b128 %0, %1 offset:" #imm_ : "=v"(dst_) : "v"(a_))
#define DSR64(dst_, a_, imm_) \
    asm volatile("ds_read_b64 %0, %1 offset:" #imm_ : "=v"(dst_) : "v"(a_))
#define GL4(d_, p_) asm volatile("global_load_dwordx4 %0, %1, off" : "=v"(d_) : "v"(p_))
#define GL2(d_, p_) asm volatile("global_load_dwordx2 %0, %1, off" : "=v"(d_) : "v"(p_))
#define DSW(a_, imm_, d_) \
    asm volatile("ds_write_b128 %0, %1 offset:" #imm_ :: "v"(a_), "v"(d_) : "memory")
#define DSW64(a_, imm_, d_) \
    asm volatile("ds_write_b64 %0, %1 offset:" #imm_ :: "v"(a_), "v"(d_) : "memory")
#define LGKM(n_) asm volatile("s_waitcnt lgkmcnt(" #n_ ")" ::: "memory")
#define VMC0 asm volatile("s_waitcnt vmcnt(0)" ::: "memory")
#define SB0 __builtin_amdgcn_sched_barrier(0)

// ---------------- bf16 reg-staged GEMM (R10, verified) ----------------
#define LOADT(T_) do {                                                     \
    const size_t ko_ = (size_t)(T_) * 64;                                  \
    GL4(ra0, pa + ko_);             GL4(ra1, pa + lda64 + ko_);            \
    GL4(ra2, pa + 2 * lda64 + ko_); GL4(ra3, pa + 3 * lda64 + ko_);        \
    GL4(rb0, pb + ko_);             GL4(rb1, pb + ldb64 + ko_);            \
    GL4(rb2, pb + 2 * ldb64 + ko_); GL4(rb3, pb + 3 * ldb64 + ko_);        \
} while (0)
#define WRITET(WB_) do {                                                   \
    const unsigned wa_ = wA + (WB_), wb2_ = wB + (WB_);                    \
    DSW(wa_, 0, ra0);     DSW(wa_, 8192, ra1);                             \
    DSW(wa_, 16384, ra2); DSW(wa_, 24576, ra3);                            \
    DSW(wb2_, 0, rb0);     DSW(wb2_, 8192, rb1);                           \
    DSW(wb2_, 16384, rb2); DSW(wb2_, 24576, rb3);                          \
} while (0)

// EPI 0: bf16 out. EPI 2: f32 = acc/aux1[row]. EPI 3: fp8-e4m3 out.
// All epilogues: per-wave LDS transpose -> coalesced 16B stores.
template <int EPI>
__global__ __launch_bounds__(512, 2) void gemm256(
    const unsigned short* __restrict__ A, int lda, long long sA,
    const unsigned short* __restrict__ B, int ldb, long long sB,
    void* __restrict__ Cv, int ldc, long long sC,
    int Kd, int perm,
    const float* __restrict__ aux1, int sAux1) {
    __shared__ __attribute__((aligned(128))) unsigned short As[2 * 256 * 64];
    __shared__ __attribute__((aligned(128))) unsigned short Bs[2 * 256 * 64];

    const int z = perm ? blockIdx.x : blockIdx.z;
    const int jb = perm ? blockIdx.y : blockIdx.x;
    const int ib = perm ? blockIdx.z : blockIdx.y;
    const unsigned short* __restrict__ Ab = A + (size_t)z * sA;
    const unsigned short* __restrict__ Bb = B + (size_t)z * sB;
    const int i0 = ib * 256, j0 = jb * 256;
    const int tid = threadIdx.x;
    const int w = tid >> 6, lane = tid & 63;
    const int wr = w >> 2, wc = w & 3;
    const int c16 = lane & 15, kq = lane >> 4;

    const int lr0 = tid >> 3;
    const int clog0 = (tid & 7) ^ (lr0 & 7);
    const unsigned short* pa = Ab + (size_t)(i0 + lr0) * lda + clog0 * 8;
    const unsigned short* pb = Bb + (size_t)(j0 + lr0) * ldb + clog0 * 8;
    const size_t lda64 = (size_t)64 * lda, ldb64 = (size_t)64 * ldb;

    const unsigned wA = lds_off(As) + (unsigned)tid * 16;
    const unsigned wB = lds_off(Bs) + (unsigned)tid * 16;

    const int swc = (kq ^ (c16 & 7)) << 4;
    const unsigned adrA0 = lds_off(As) + (unsigned)(wr * 128 + c16) * 128 + swc;
    const unsigned adrA0x = adrA0 ^ 64u;
    const unsigned adrB0 = lds_off(Bs) + (unsigned)(wc * 64 + c16) * 128 + swc;
    const unsigned adrB0x = adrB0 ^ 64u;

    f32x4 acc[8][4];
    const f32x4 zero = {0.f, 0.f, 0.f, 0.f};
#pragma unroll
    for (int i = 0; i < 8; ++i)
#pragma unroll
        for (int j = 0; j < 4; ++j) acc[i][j] = zero;

    u32x4 ra0, ra1, ra2, ra3, rb0, rb1, rb2, rb3;
    bf16x8 aL[4][2], aH[4][2], bF[4][2];

    const int nt = Kd >> 6;

    LOADT(0);
    VMC0;
    WRITET(0u);
    LOADT(1);
    LGKM(0);
    wg_barrier();

    for (int t = 0; t < nt; ++t) {
        const unsigned rb_ = (t & 1) ? 32768u : 0u;
        const unsigned wb_ = (t & 1) ? 0u : 32768u;
        const unsigned aA = adrA0 + rb_, aAx = adrA0x + rb_;
        const unsigned aB = adrB0 + rb_, aBx = adrB0x + rb_;
        DSR(aL[0][0], aA, 0);    DSR(aL[0][1], aAx, 0);
        DSR(aL[1][0], aA, 2048); DSR(aL[1][1], aAx, 2048);
        DSR(aL[2][0], aA, 4096); DSR(aL[2][1], aAx, 4096);
        DSR(aL[3][0], aA, 6144); DSR(aL[3][1], aAx, 6144);
        DSR(bF[0][0], aB, 0);    DSR(bF[0][1], aBx, 0);
        DSR(bF[1][0], aB, 2048); DSR(bF[1][1], aBx, 2048);
        DSR(bF[2][0], aB, 4096); DSR(bF[2][1], aBx, 4096);
        DSR(bF[3][0], aB, 6144); DSR(bF[3][1], aBx, 6144);
        if (t + 1 < nt) {
            VMC0;
            WRITET(wb_);
            if (t + 2 < nt) LOADT(t + 2);
            LGKM(8);
        } else {
            LGKM(0);
        }
        SB0;
        __builtin_amdgcn_s_setprio(1);
#pragma unroll
        for (int kk = 0; kk < 2; ++kk)
#pragma unroll
            for (int mi = 0; mi < 4; ++mi)
#pragma unroll
                for (int ni = 0; ni < 4; ++ni)
                    MF(aL[mi][kk], bF[ni][kk], acc[mi][ni]);
        __builtin_amdgcn_s_setprio(0);
        DSR(aH[0][0], aA, 8192);  DSR(aH[0][1], aAx, 8192);
        DSR(aH[1][0], aA, 10240); DSR(aH[1][1], aAx, 10240);
        DSR(aH[2][0], aA, 12288); DSR(aH[2][1], aAx, 12288);
        DSR(aH[3][0], aA, 14336); DSR(aH[3][1], aAx, 14336);
        LGKM(0); SB0;
        __builtin_amdgcn_s_setprio(1);
#pragma unroll
        for (int kk = 0; kk < 2; ++kk)
#pragma unroll
            for (int mi = 0; mi < 4; ++mi)
#pragma unroll
                for (int ni = 0; ni < 4; ++ni)
                    MF(aH[mi][kk], bF[ni][kk], acc[4 + mi][ni]);
        __builtin_amdgcn_s_setprio(0);
        wg_barrier();
    }
    // K-loop done; LDS dead -> per-wave scratch region (8 KiB each in As)
    const int prow = kq * 4;
    if constexpr (EPI == 0) {
        unsigned short* C = (unsigned short*)Cv + (size_t)z * sC;
        unsigned short* sc = (unsigned short*)((char*)As + w * 8192);  // 16x72 shorts
        const int rr = lane >> 3, ch = lane & 7;
#pragma unroll
        for (int mi = 0; mi < 8; ++mi) {
#pragma unroll
            for (int ni = 0; ni < 4; ++ni)
#pragma unroll
                for (int r = 0; r < 4; ++r)
                    sc[(prow + r) * 72 + ni * 16 + c16] = f2b(acc[mi][ni][r]);
#pragma unroll
            for (int pass = 0; pass < 2; ++pass) {
                const int r2 = rr + 8 * pass;
                bf16x8 v = *(const bf16x8*)&sc[r2 * 72 + ch * 8];
                const int grow = i0 + wr * 128 + mi * 16 + r2;
                *(bf16x8*)&C[(size_t)grow * ldc + j0 + wc * 64 + ch * 8] = v;
            }
        }
    } else if constexpr (EPI == 3) {
        unsigned char* C = (unsigned char*)Cv + (size_t)z * sC;
        unsigned char* sc = (unsigned char*)As + w * 8192;  // 16x80 bytes
        const int rr = lane >> 2, ch = lane & 3;
#pragma unroll
        for (int mi = 0; mi < 8; ++mi) {
#pragma unroll
            for (int ni = 0; ni < 4; ++ni)
#pragma unroll
                for (int r = 0; r < 4; ++r)
                    sc[(prow + r) * 80 + ni * 16 + c16] = f2f8(acc[mi][ni][r]);
            u32x4 v = *(const u32x4*)&sc[rr * 80 + ch * 16];
            const int grow = i0 + wr * 128 + mi * 16 + rr;
            *(u32x4*)&C[(size_t)grow * ldc + j0 + wc * 64 + ch * 16] = v;
        }
    } else {
        float* C = (float*)Cv + (size_t)z * sC;
        const float* lb = aux1 + (size_t)z * sAux1;
        float* sc = (float*)((char*)As + w * 8192);  // 16x68 floats = 4352 B
        const int rr = lane >> 4, ch = lane & 15;
#pragma unroll
        for (int mi = 0; mi < 8; ++mi) {
#pragma unroll
            for (int ni = 0; ni < 4; ++ni)
#pragma unroll
                for (int r = 0; r < 4; ++r) {
                    const int grow = i0 + wr * 128 + mi * 16 + prow + r;
                    sc[(prow + r) * 68 + ni * 16 + c16] = acc[mi][ni][r] / lb[grow];
                }
#pragma unroll
            for (int pass = 0; pass < 4; ++pass) {
                const int r2 = rr + 4 * pass;
                f32x4 v = *(const f32x4*)&sc[r2 * 68 + ch * 4];
                const int grow = i0 + wr * 128 + mi * 16 + r2;
                *(f32x4*)&C[(size_t)grow * ldc + j0 + wc * 64 + ch * 4] = v;
            }
        }
    }
}

// ---------------- fp8 scores GEMM (reg-staged, 8B-slot swizzle) ----------------
#define LOADT8(T_) do {                                                    \
    const size_t ko_ = (size_t)(T_) * 64;                                  \
    GL2(fa0, pa8 + ko_);              GL2(fa1, pa8 + lda64b + ko_);        \
    GL2(fa2, pa8 + 2 * lda64b + ko_); GL2(fa3, pa8 + 3 * lda64b + ko_);    \
    GL2(fb0, pb8 + ko_);              GL2(fb1, pb8 + ldb64b + ko_);        \
    GL2(fb2, pb8 + 2 * ldb64b + ko_); GL2(fb3, pb8 + 3 * ldb64b + ko_);    \
} while (0)
#define WRITET8(WB_) do {                                                  \
    const unsigned wa_ = wA8 + (WB_), wb2_ = wB8 + (WB_);                  \
    DSW64(wa_, 0, fa0);     DSW64(wa_, 4096, fa1);                         \
    DSW64(wa_, 8192, fa2);  DSW64(wa_, 12288, fa3);                        \
    DSW64(wb2_, 0, fb0);    DSW64(wb2_, 4096, fb1);                        \
    DSW64(wb2_, 8192, fb2); DSW64(wb2_, 12288, fb3);                       \
} while (0)

__global__ __launch_bounds__(512, 2) void gemm256f8(
    const unsigned char* __restrict__ A, int lda, long long sA,
    const unsigned char* __restrict__ B, int ldb, long long sB,
    unsigned short* __restrict__ Cq, int ldc, long long sC,
    int Kd,
    const float* __restrict__ q2a, int sQ2,
    const float* __restrict__ k2a, int sK2,
    float invs) {
    __shared__ __attribute__((aligned(128))) unsigned char As8[2 * 256 * 64];
    __shared__ __attribute__((aligned(128))) unsigned char Bs8[2 * 256 * 64];

    const int z = blockIdx.x;        // XCD i owns batch i
    const int jb = blockIdx.y, ib = blockIdx.z;
    const unsigned char* __restrict__ Ab = A + (size_t)z * sA;
    const unsigned char* __restrict__ Bb = B + (size_t)z * sB;
    const int i0 = ib * 256, j0 = jb * 256;
    const int tid = threadIdx.x;
    const int w = tid >> 6, lane = tid & 63;
    const int wr = w >> 2, wc = w & 3;
    const int c16 = lane & 15, kq = lane >> 4;

    const int lr0 = tid >> 3;
    const int slog = (tid & 7) ^ (lr0 & 7);
    const unsigned char* pa8 = Ab + (size_t)(i0 + lr0) * lda + slog * 8;
    const unsigned char* pb8 = Bb + (size_t)(j0 + lr0) * ldb + slog * 8;
    const size_t lda64b = (size_t)64 * lda, ldb64b = (size_t)64 * ldb;

    const unsigned wA8 = lds_off(As8) + (unsigned)tid * 8;
    const unsigned wB8 = lds_off(Bs8) + (unsigned)tid * 8;

    const int sw8 = (kq ^ (c16 & 7)) << 3;
    const unsigned adrA0 = lds_off(As8) + (unsigned)(wr * 128 + c16) * 64 + sw8;
    const unsigned adrA0x = adrA0 ^ 32u;
    const unsigned adrB0 = lds_off(Bs8) + (unsigned)(wc * 64 + c16) * 64 + sw8;
    const unsigned adrB0x = adrB0 ^ 32u;

    f32x4 acc[8][4];
    const f32x4 zero = {0.f, 0.f, 0.f, 0.f};
#pragma unroll
    for (int i = 0; i < 8; ++i)
#pragma unroll
        for (int j = 0; j < 4; ++j) acc[i][j] = zero;

    u32x2 fa0, fa1, fa2, fa3, fb0, fb1, fb2, fb3;
    long aL[4][2], aH[4][2], bF[4][2];

    const int nt = Kd >> 6;

    LOADT8(0);
    VMC0;
    WRITET8(0u);
    LOADT8(1);
    LGKM(0);
    wg_barrier();

    for (int t = 0; t < nt; ++t) {
        const unsigned rb_ = (t & 1) ? 16384u : 0u;
        const unsigned wb_ = (t & 1) ? 0u : 16384u;
        const unsigned aA = adrA0 + rb_, aAx = adrA0x + rb_;
        const unsigned aB = adrB0 + rb_, aBx = adrB0x + rb_;
        DSR64(aL[0][0], aA, 0);    DSR64(aL[0][1], aAx, 0);
        DSR64(aL[1][0], aA, 1024); DSR64(aL[1][1], aAx, 1024);
        DSR64(aL[2][0], aA, 2048); DSR64(aL[2][1], aAx, 2048);
        DSR64(aL[3][0], aA, 3072); DSR64(aL[3][1], aAx, 3072);
        DSR64(bF[0][0], aB, 0);    DSR64(bF[0][1], aBx, 0);
        DSR64(bF[1][0], aB, 1024); DSR64(bF[1][1], aBx, 1024);
        DSR64(bF[2][0], aB, 2048); DSR64(bF[2][1], aBx, 2048);
        DSR64(bF[3][0], aB, 3072); DSR64(bF[3][1], aBx, 3072);
        if (t + 1 < nt) {
            VMC0;
            WRITET8(wb_);
            if (t + 2 < nt) LOADT8(t + 2);
            LGKM(8);
        } else {
            LGKM(0);
        }
        SB0;
        __builtin_amdgcn_s_setprio(1);
#pragma unroll
        for (int kk = 0; kk < 2; ++kk)
#pragma unroll
            for (int mi = 0; mi < 4; ++mi)
#pragma unroll
                for (int ni = 0; ni < 4; ++ni)
                    MF8(aL[mi][kk], bF[ni][kk], acc[mi][ni]);
        __builtin_amdgcn_s_setprio(0);
        DSR64(aH[0][0], aA, 4096); DSR64(aH[0][1], aAx, 4096);
        DSR64(aH[1][0], aA, 5120); DSR64(aH[1][1], aAx, 5120);
        DSR64(aH[2][0], aA, 6144); DSR64(aH[2][1], aAx, 6144);
        DSR64(aH[3][0], aA, 7168); DSR64(aH[3][1], aAx, 7168);
        LGKM(0); SB0;
        __builtin_amdgcn_s_setprio(1);
#pragma unroll
        for (int kk = 0; kk < 2; ++kk)
#pragma unroll
            for (int mi = 0; mi < 4; ++mi)
#pragma unroll
                for (int ni = 0; ni < 4; ++ni)
                    MF8(aH[mi][kk], bF[ni][kk], acc[4 + mi][ni]);
        __builtin_amdgcn_s_setprio(0);
        wg_barrier();
    }

    // scores epilogue: E = exp(sqrt(max(q2+k2-2*acc,0))*invs) -> bf16,
    // via per-wave LDS transpose (4 KiB region in dead As8) -> 16B stores.
    unsigned short* C = Cq + (size_t)z * sC;
    const float* q2b = q2a + (size_t)z * sQ2;
    const float* k2b = k2a + (size_t)z * sK2;
    unsigned short* sc = (unsigned short*)(As8 + w * 4096);  // 16x72 shorts = 2304 B
    const int prow = kq * 4;
    const int rr = lane >> 3, ch = lane & 7;
#pragma unroll
    for (int mi = 0; mi < 8; ++mi) {
#pragma unroll
        for (int ni = 0; ni < 4; ++ni) {
            const int col = j0 + wc * 64 + ni * 16 + c16;
            const float k2v = k2b[col];
#pragma unroll
            for (int r = 0; r < 4; ++r) {
                const int grow = i0 + wr * 128 + mi * 16 + prow + r;
                float d2 = q2b[grow] + k2v - 2.0f * acc[mi][ni][r];
                float e = __expf(sqrtf(fmaxf(d2, 0.f)) * invs);
                sc[(prow + r) * 72 + ni * 16 + c16] = f2b(e);
            }
        }
#pragma unroll
        for (int pass = 0; pass < 2; ++pass) {
            const int r2 = rr + 8 * pass;
            bf16x8 v = *(const bf16x8*)&sc[r2 * 72 + ch * 8];
            const int grow = i0 + wr * 128 + mi * 16 + r2;
            *(bf16x8*)&C[(size_t)grow * ldc + j0 + wc * 64 + ch * 8] = v;
        }
    }
}

extern "C" void kernel_launch(void* const* d_in, const int* in_sizes, int n_in,
                              void* d_out, int out_size, void* d_ws, size_t ws_size,
                              hipStream_t stream) {
    const float* x = (const float*)d_in[0];
    const float* Wq = (const float*)d_in[1];
    const float* Wk = (const float*)d_in[2];
    const float* Wv = (const float*)d_in[3];
    const int Bz = 8, S = 2048, D = 768, F = 768;
    const int BS = Bz * S;  // 16384

    const size_t szX = (size_t)BS * D * 2;
    const size_t szW = (size_t)F * D * 2;
    const size_t szQ8 = (size_t)BS * F;
    const size_t szE = (size_t)Bz * S * S * 2;

    char* p = (char*)d_ws;
    unsigned short* xb = (unsigned short*)p;  p += szX;
    unsigned short* Wqb = (unsigned short*)p; p += szW;
    unsigned short* Wkb = (unsigned short*)p; p += szW;
    unsigned short* Wvb = (unsigned short*)p; p += szW;
    unsigned char* Q8 = (unsigned char*)p;    p += szQ8;
    unsigned char* K8 = (unsigned char*)p;    p += szQ8;
    unsigned short* VT = (unsigned short*)p;  p += szX;   // [F][BS]
    unsigned short* E = (unsigned short*)p;   p += szE;   // [Bz][S][S]
    float* q2 = (float*)p;   p += (size_t)BS * 4;
    float* k2 = (float*)p;   p += (size_t)BS * 4;
    float* lsum = (float*)p; p += (size_t)BS * 4;
    if ((size_t)(p - (char*)d_ws) > ws_size) return;  // ~147 MiB scratch required

    const float invs = 1.0f / sqrtf(768.0f);

    // 1) casts
    castk<<<(BS * D / 4 + 255) / 256, 256, 0, stream>>>(x, xb, BS * D / 4);
    castk<<<(F * D / 4 + 255) / 256, 256, 0, stream>>>(Wq, Wqb, F * D / 4);
    castk<<<(F * D / 4 + 255) / 256, 256, 0, stream>>>(Wk, Wkb, F * D / 4);
    castk<<<(F * D / 4 + 255) / 256, 256, 0, stream>>>(Wv, Wvb, F * D / 4);

    // 2) Q8,K8 = e4m3(x . W^T)  (z=0 -> Wq->Q8, z=1 -> Wk->K8)
    gemm256<3><<<dim3(F / 256, BS / 256, 2), 512, 0, stream>>>(
        xb, D, 0,
        Wqb, D, (long long)F * D,
        Q8, F, (long long)BS * F,
        D, 0, nullptr, 0);

    //    V^T = Wv . x^T   -> VT[f][s] (bf16)
    gemm256<0><<<dim3(BS / 256, F / 256, 1), 512, 0, stream>>>(
        Wvb, D, 0,
        xb, D, 0,
        VT, BS, 0,
        D, 0, nullptr, 0);

    // 3) q2,k2 from the fp8-rounded values (exact consistency with fp8 MFMA)
    rowreduce8<<<BS / 4, 256, 0, stream>>>(Q8, F, BS, q2);
    rowreduce8<<<BS / 4, 256, 0, stream>>>(K8, F, BS, k2);

    // 4) E = exp(sqrt(max(q2+k2-2*Q8.K8^T,0))*invs); x=batch -> XCD-pinned
    gemm256f8<<<dim3(Bz, S / 256, S / 256), 512, 0, stream>>>(
        Q8, F, (long long)S * F,
        K8, F, (long long)S * F,
        E, S, (long long)S * S,
        F, q2, S, k2, S, invs);

    // 5) l = rowsum(E)
    rowreduce<0><<<BS / 4, 256, 0, stream>>>(E, S, BS, lsum);

    // 6) out = (E . V) / l; x=batch -> XCD reads the E_z it just wrote
    gemm256<2><<<dim3(Bz, F / 256, S / 256), 512, 0, stream>>>(
        E, S, (long long)S * S,
        VT, BS, (long long)S,
        d_out, F, (long long)S * F,
        S, 1, lsum, S);
}

// Round 13
// 240.596 us; speedup vs baseline: 1.4196x; 1.0178x over previous
//
#include <hip/hip_runtime.h>
#include <hip/hip_fp8.h>
#include <stdint.h>
#include <math.h>

// cdist-attention. R13: instruction-rate model of vmem (≈100 cyc per wave-load
// instr regardless of 8/16 B per lane; fits R7/R8/R10/R11/PV exactly).
// Levers: (1) fp8 scores staging via GL4 (16 B/lane -> 32 instrs/tile instead
// of 64), new 16B-slot swizzle s = p ^ (row&3) ^ ((row>>2)&1) (b64 reads hit
// every bank exactly 4x = wave floor; kk=1 = addr^32). (2) depth-2 register
// prefetch (two GL4 reg sets, vmcnt(4)): loads issued ~1.5 tiles before use
// (R10's "full tile" was really half a tile of compute -> stall).
// (3) lsum fused into scores epilogue (shfl+atomicAdd); rowreduce<0> dropped.
// bf16 gemm256 identical to R12 (verified).

typedef __attribute__((ext_vector_type(8))) __bf16 bf16x8;
typedef __attribute__((ext_vector_type(4))) float f32x4;
typedef __attribute__((ext_vector_type(4))) unsigned int u32x4;

__device__ __forceinline__ unsigned short f2b(float f) {
    unsigned u = __float_as_uint(f);
    unsigned r = 0x7fffu + ((u >> 16) & 1u);
    return (unsigned short)((u + r) >> 16);
}
__device__ __forceinline__ float b2f(unsigned short h) {
    return __uint_as_float(((unsigned)h) << 16);
}
__device__ __forceinline__ unsigned char f2f8(float f) {
    __hip_fp8_e4m3 t(f);
    return t.__x;
}
__device__ __forceinline__ float f8tof(unsigned char b) {
    int e = (b >> 3) & 15, m = b & 7;
    float v = e ? ldexpf(8.0f + m, e - 10) : ldexpf((float)m, -9);
    return (b & 0x80) ? -v : v;
}

__device__ __forceinline__ void wg_barrier() {
    asm volatile("" ::: "memory");
    __builtin_amdgcn_s_barrier();
    asm volatile("" ::: "memory");
}

__device__ __forceinline__ unsigned lds_off(const void* p) {
    return (unsigned)(uintptr_t)(const __attribute__((address_space(3))) char*)p;
}

__global__ __launch_bounds__(256) void castk(const float* __restrict__ src,
                                             unsigned short* __restrict__ dst, int n4) {
    int i = blockIdx.x * 256 + threadIdx.x;
    if (i >= n4) return;
    float4 v = ((const float4*)src)[i];
    ushort4 o;
    o.x = f2b(v.x); o.y = f2b(v.y); o.z = f2b(v.z); o.w = f2b(v.w);
    ((ushort4*)dst)[i] = o;
}

__global__ __launch_bounds__(256) void zerok(float* __restrict__ p, int n) {
    int i = blockIdx.x * 256 + threadIdx.x;
    if (i < n) p[i] = 0.f;
}

// row sum of squares over fp8-e4m3 rows (consistency with fp8 MFMA operands)
__global__ __launch_bounds__(256) void rowreduce8(const unsigned char* __restrict__ X,
                                                  int L, int rows, float* __restrict__ out) {
    int w = threadIdx.x >> 6, lane = threadIdx.x & 63;
    int row = blockIdx.x * 4 + w;
    if (row >= rows) return;
    const unsigned char* xr = X + (size_t)row * L;
    float s = 0.f;
    int passes = L >> 8;
    for (int p = 0; p < passes; ++p) {
        uchar4 u = *(const uchar4*)(xr + (p << 8) + lane * 4);
        float a = f8tof(u.x), b = f8tof(u.y), c = f8tof(u.z), d = f8tof(u.w);
        s += a * a + b * b + c * c + d * d;
    }
#pragma unroll
    for (int o = 32; o > 0; o >>= 1) s += __shfl_down(s, o);
    if (lane == 0) out[row] = s;
}

#define MF(A_, B_, C_) (C_) = __builtin_amdgcn_mfma_f32_16x16x32_bf16((A_), (B_), (C_), 0, 0, 0)
#define MF8(A_, B_, C_) (C_) = __builtin_amdgcn_mfma_f32_16x16x32_fp8_fp8((A_), (B_), (C_), 0, 0, 0)
#define DSR(dst_, a_, imm_) \
    asm volatile("ds_read_b128 %0, %1 offset:" #imm_ : "=v"(dst_) : "v"(a_))
#define DSR64(dst_, a_, imm_) \
    asm volatile("ds_read_b64 %0, %1 offset:" #imm_ : "=v"(dst_) : "v"(a_))
#define GL4(d_, p_) asm volatile("global_load_dwordx4 %0, %1, off" : "=v"(d_) : "v"(p_))
#define DSW(a_, imm_, d_) \
    asm volatile("ds_write_b128 %0, %1 offset:" #imm_ :: "v"(a_), "v"(d_) : "memory")
#define LGKM(n_) asm volatile("s_waitcnt lgkmcnt(" #n_ ")" ::: "memory")
#define VMC4 asm volatile("s_waitcnt vmcnt(4)" ::: "memory")
#define VMC0 asm volatile("s_waitcnt vmcnt(0)" ::: "memory")
#define SB0 __builtin_amdgcn_sched_barrier(0)

// ---------------- bf16 reg-staged GEMM (R12, verified) ----------------
#define LOADT(T_) do {                                                     \
    const size_t ko_ = (size_t)(T_) * 64;                                  \
    GL4(ra0, pa + ko_);             GL4(ra1, pa + lda64 + ko_);            \
    GL4(ra2, pa + 2 * lda64 + ko_); GL4(ra3, pa + 3 * lda64 + ko_);        \
    GL4(rb0, pb + ko_);             GL4(rb1, pb + ldb64 + ko_);            \
    GL4(rb2, pb + 2 * ldb64 + ko_); GL4(rb3, pb + 3 * ldb64 + ko_);        \
} while (0)
#define WRITET(WB_) do {                                                   \
    const unsigned wa_ = wA + (WB_), wb2_ = wB + (WB_);                    \
    DSW(wa_, 0, ra0);     DSW(wa_, 8192, ra1);                             \
    DSW(wa_, 16384, ra2); DSW(wa_, 24576, ra3);                            \
    DSW(wb2_, 0, rb0);     DSW(wb2_, 8192, rb1);                           \
    DSW(wb2_, 16384, rb2); DSW(wb2_, 24576, rb3);                          \
} while (0)

// EPI 0: bf16 out. EPI 2: f32 = acc/aux1[row]. EPI 3: fp8-e4m3 out.
template <int EPI>
__global__ __launch_bounds__(512, 2) void gemm256(
    const unsigned short* __restrict__ A, int lda, long long sA,
    const unsigned short* __restrict__ B, int ldb, long long sB,
    void* __restrict__ Cv, int ldc, long long sC,
    int Kd, int perm,
    const float* __restrict__ aux1, int sAux1) {
    __shared__ __attribute__((aligned(128))) unsigned short As[2 * 256 * 64];
    __shared__ __attribute__((aligned(128))) unsigned short Bs[2 * 256 * 64];

    const int z = perm ? blockIdx.x : blockIdx.z;
    const int jb = perm ? blockIdx.y : blockIdx.x;
    const int ib = perm ? blockIdx.z : blockIdx.y;
    const unsigned short* __restrict__ Ab = A + (size_t)z * sA;
    const unsigned short* __restrict__ Bb = B + (size_t)z * sB;
    const int i0 = ib * 256, j0 = jb * 256;
    const int tid = threadIdx.x;
    const int w = tid >> 6, lane = tid & 63;
    const int wr = w >> 2, wc = w & 3;
    const int c16 = lane & 15, kq = lane >> 4;

    const int lr0 = tid >> 3;
    const int clog0 = (tid & 7) ^ (lr0 & 7);
    const unsigned short* pa = Ab + (size_t)(i0 + lr0) * lda + clog0 * 8;
    const unsigned short* pb = Bb + (size_t)(j0 + lr0) * ldb + clog0 * 8;
    const size_t lda64 = (size_t)64 * lda, ldb64 = (size_t)64 * ldb;

    const unsigned wA = lds_off(As) + (unsigned)tid * 16;
    const unsigned wB = lds_off(Bs) + (unsigned)tid * 16;

    const int swc = (kq ^ (c16 & 7)) << 4;
    const unsigned adrA0 = lds_off(As) + (unsigned)(wr * 128 + c16) * 128 + swc;
    const unsigned adrA0x = adrA0 ^ 64u;
    const unsigned adrB0 = lds_off(Bs) + (unsigned)(wc * 64 + c16) * 128 + swc;
    const unsigned adrB0x = adrB0 ^ 64u;

    f32x4 acc[8][4];
    const f32x4 zero = {0.f, 0.f, 0.f, 0.f};
#pragma unroll
    for (int i = 0; i < 8; ++i)
#pragma unroll
        for (int j = 0; j < 4; ++j) acc[i][j] = zero;

    u32x4 ra0, ra1, ra2, ra3, rb0, rb1, rb2, rb3;
    bf16x8 aL[4][2], aH[4][2], bF[4][2];

    const int nt = Kd >> 6;

    LOADT(0);
    VMC0;
    WRITET(0u);
    LOADT(1);
    LGKM(0);
    wg_barrier();

    for (int t = 0; t < nt; ++t) {
        const unsigned rb_ = (t & 1) ? 32768u : 0u;
        const unsigned wb_ = (t & 1) ? 0u : 32768u;
        const unsigned aA = adrA0 + rb_, aAx = adrA0x + rb_;
        const unsigned aB = adrB0 + rb_, aBx = adrB0x + rb_;
        DSR(aL[0][0], aA, 0);    DSR(aL[0][1], aAx, 0);
        DSR(aL[1][0], aA, 2048); DSR(aL[1][1], aAx, 2048);
        DSR(aL[2][0], aA, 4096); DSR(aL[2][1], aAx, 4096);
        DSR(aL[3][0], aA, 6144); DSR(aL[3][1], aAx, 6144);
        DSR(bF[0][0], aB, 0);    DSR(bF[0][1], aBx, 0);
        DSR(bF[1][0], aB, 2048); DSR(bF[1][1], aBx, 2048);
        DSR(bF[2][0], aB, 4096); DSR(bF[2][1], aBx, 4096);
        DSR(bF[3][0], aB, 6144); DSR(bF[3][1], aBx, 6144);
        if (t + 1 < nt) {
            VMC0;
            WRITET(wb_);
            if (t + 2 < nt) LOADT(t + 2);
            LGKM(8);
        } else {
            LGKM(0);
        }
        SB0;
        __builtin_amdgcn_s_setprio(1);
#pragma unroll
        for (int kk = 0; kk < 2; ++kk)
#pragma unroll
            for (int mi = 0; mi < 4; ++mi)
#pragma unroll
                for (int ni = 0; ni < 4; ++ni)
                    MF(aL[mi][kk], bF[ni][kk], acc[mi][ni]);
        __builtin_amdgcn_s_setprio(0);
        DSR(aH[0][0], aA, 8192);  DSR(aH[0][1], aAx, 8192);
        DSR(aH[1][0], aA, 10240); DSR(aH[1][1], aAx, 10240);
        DSR(aH[2][0], aA, 12288); DSR(aH[2][1], aAx, 12288);
        DSR(aH[3][0], aA, 14336); DSR(aH[3][1], aAx, 14336);
        LGKM(0); SB0;
        __builtin_amdgcn_s_setprio(1);
#pragma unroll
        for (int kk = 0; kk < 2; ++kk)
#pragma unroll
            for (int mi = 0; mi < 4; ++mi)
#pragma unroll
                for (int ni = 0; ni < 4; ++ni)
                    MF(aH[mi][kk], bF[ni][kk], acc[4 + mi][ni]);
        __builtin_amdgcn_s_setprio(0);
        wg_barrier();
    }
    // epilogues: per-wave LDS transpose -> coalesced 16B stores (R12)
    const int prow = kq * 4;
    if constexpr (EPI == 0) {
        unsigned short* C = (unsigned short*)Cv + (size_t)z * sC;
        unsigned short* sc = (unsigned short*)((char*)As + w * 8192);  // 16x72
        const int rr = lane >> 3, ch = lane & 7;
#pragma unroll
        for (int mi = 0; mi < 8; ++mi) {
#pragma unroll
            for (int ni = 0; ni < 4; ++ni)
#pragma unroll
                for (int r = 0; r < 4; ++r)
                    sc[(prow + r) * 72 + ni * 16 + c16] = f2b(acc[mi][ni][r]);
#pragma unroll
            for (int pass = 0; pass < 2; ++pass) {
                const int r2 = rr + 8 * pass;
                bf16x8 v = *(const bf16x8*)&sc[r2 * 72 + ch * 8];
                const int grow = i0 + wr * 128 + mi * 16 + r2;
                *(bf16x8*)&C[(size_t)grow * ldc + j0 + wc * 64 + ch * 8] = v;
            }
        }
    } else if constexpr (EPI == 3) {
        unsigned char* C = (unsigned char*)Cv + (size_t)z * sC;
        unsigned char* sc = (unsigned char*)As + w * 8192;  // 16x80 bytes
        const int rr = lane >> 2, ch = lane & 3;
#pragma unroll
        for (int mi = 0; mi < 8; ++mi) {
#pragma unroll
            for (int ni = 0; ni < 4; ++ni)
#pragma unroll
                for (int r = 0; r < 4; ++r)
                    sc[(prow + r) * 80 + ni * 16 + c16] = f2f8(acc[mi][ni][r]);
            u32x4 v = *(const u32x4*)&sc[rr * 80 + ch * 16];
            const int grow = i0 + wr * 128 + mi * 16 + rr;
            *(u32x4*)&C[(size_t)grow * ldc + j0 + wc * 64 + ch * 16] = v;
        }
    } else {
        float* C = (float*)Cv + (size_t)z * sC;
        const float* lb = aux1 + (size_t)z * sAux1;
        float* sc = (float*)((char*)As + w * 8192);  // 16x68 floats
        const int rr = lane >> 4, ch = lane & 15;
#pragma unroll
        for (int mi = 0; mi < 8; ++mi) {
#pragma unroll
            for (int ni = 0; ni < 4; ++ni)
#pragma unroll
                for (int r = 0; r < 4; ++r) {
                    const int grow = i0 + wr * 128 + mi * 16 + prow + r;
                    sc[(prow + r) * 68 + ni * 16 + c16] = acc[mi][ni][r] / lb[grow];
                }
#pragma unroll
            for (int pass = 0; pass < 4; ++pass) {
                const int r2 = rr + 4 * pass;
                f32x4 v = *(const f32x4*)&sc[r2 * 68 + ch * 4];
                const int grow = i0 + wr * 128 + mi * 16 + r2;
                *(f32x4*)&C[(size_t)grow * ldc + j0 + wc * 64 + ch * 4] = v;
            }
        }
    }
}

// -------- fp8 scores GEMM: GL4 staging, 16B-slot swizzle, depth-2 prefetch --------
// LDS image per buf: [256 rows][64 B]; 16B-slot s stores logical chunk
// p = s ^ (row&3) ^ ((row>>2)&1). Staging: thread t -> rows t>>2 (+128),
// stored slot t&3 -> LDS linear t*16 (+8192). Reads: b64 at
// row*64 + (((kq>>1)^gl)<<4) + ((kq&1)<<3), gl=(c16&3)^((c16>>2)&1);
// kk=1 -> ^32; mi/ni -> +1024 imm. Bank check: every bank hit exactly 4x
// (= 512B/wave b64 floor) -> conflict-free.
#define LOADT8F(T_) do {                                                   \
    const size_t ko_ = (size_t)(T_) * 64;                                  \
    GL4(fa0, pa8 + ko_); GL4(fa1, pa8 + lda128 + ko_);                     \
    GL4(fb0, pb8 + ko_); GL4(fb1, pb8 + ldb128 + ko_);                     \
} while (0)
#define LOADT8G(T_) do {                                                   \
    const size_t ko_ = (size_t)(T_) * 64;                                  \
    GL4(ga0, pa8 + ko_); GL4(ga1, pa8 + lda128 + ko_);                     \
    GL4(gb0, pb8 + ko_); GL4(gb1, pb8 + ldb128 + ko_);                     \
} while (0)
#define WRITET8F(WB_) do {                                                 \
    DSW(wA8 + (WB_), 0, fa0); DSW(wA8 + (WB_), 8192, fa1);                 \
    DSW(wB8 + (WB_), 0, fb0); DSW(wB8 + (WB_), 8192, fb1);                 \
} while (0)
#define WRITET8G(WB_) do {                                                 \
    DSW(wA8 + (WB_), 0, ga0); DSW(wA8 + (WB_), 8192, ga1);                 \
    DSW(wB8 + (WB_), 0, gb0); DSW(wB8 + (WB_), 8192, gb1);                 \
} while (0)

// One K-tile: RB_=read buf byte base, WB_=write buf base (tile TT_+1),
// WSET_/LSET_ = reg-set macros for tile TT_+1 (write) / TT_+3 (load).
#define TILE8(RB_, WB_, WSET_, LSET_, TT_) do {                            \
    const unsigned aA = adrA80 + (RB_), aAx = aA ^ 32u;                    \
    const unsigned aB = adrB80 + (RB_), aBx = aB ^ 32u;                    \
    DSR64(aL[0][0], aA, 0);    DSR64(aL[0][1], aAx, 0);                    \
    DSR64(aL[1][0], aA, 1024); DSR64(aL[1][1], aAx, 1024);                 \
    DSR64(aL[2][0], aA, 2048); DSR64(aL[2][1], aAx, 2048);                 \
    DSR64(aL[3][0], aA, 3072); DSR64(aL[3][1], aAx, 3072);                 \
    DSR64(bF[0][0], aB, 0);    DSR64(bF[0][1], aBx, 0);                    \
    DSR64(bF[1][0], aB, 1024); DSR64(bF[1][1], aBx, 1024);                 \
    DSR64(bF[2][0], aB, 2048); DSR64(bF[2][1], aBx, 2048);                 \
    DSR64(bF[3][0], aB, 3072); DSR64(bF[3][1], aBx, 3072);                 \
    if ((TT_) + 3 < nt) { VMC4; WSET_(WB_); LSET_((TT_) + 3); LGKM(4); }   \
    else if ((TT_) + 1 < nt) { VMC0; WSET_(WB_); LGKM(4); }                \
    else { LGKM(0); }                                                      \
    SB0;                                                                   \
    __builtin_amdgcn_s_setprio(1);                                         \
    _Pragma("unroll") for (int kk = 0; kk < 2; ++kk)                       \
        _Pragma("unroll") for (int mi = 0; mi < 4; ++mi)                   \
            _Pragma("unroll") for (int ni = 0; ni < 4; ++ni)               \
                MF8(aL[mi][kk], bF[ni][kk], acc[mi][ni]);                  \
    __builtin_amdgcn_s_setprio(0);                                         \
    DSR64(aH[0][0], aA, 4096); DSR64(aH[0][1], aAx, 4096);                 \
    DSR64(aH[1][0], aA, 5120); DSR64(aH[1][1], aAx, 5120);                 \
    DSR64(aH[2][0], aA, 6144); DSR64(aH[2][1], aAx, 6144);                 \
    DSR64(aH[3][0], aA, 7168); DSR64(aH[3][1], aAx, 7168);                 \
    LGKM(0); SB0;                                                          \
    __builtin_amdgcn_s_setprio(1);                                         \
    _Pragma("unroll") for (int kk = 0; kk < 2; ++kk)                       \
        _Pragma("unroll") for (int mi = 0; mi < 4; ++mi)                   \
            _Pragma("unroll") for (int ni = 0; ni < 4; ++ni)               \
                MF8(aH[mi][kk], bF[ni][kk], acc[4 + mi][ni]);              \
    __builtin_amdgcn_s_setprio(0);                                         \
    wg_barrier();                                                          \
} while (0)

__global__ __launch_bounds__(512, 2) void gemm256f8(
    const unsigned char* __restrict__ A, int lda, long long sA,
    const unsigned char* __restrict__ B, int ldb, long long sB,
    unsigned short* __restrict__ Cq, int ldc, long long sC,
    int Kd,
    const float* __restrict__ q2a, int sQ2,
    const float* __restrict__ k2a, int sK2,
    float* __restrict__ lsum, float invs) {
    __shared__ __attribute__((aligned(128))) unsigned char As8[2 * 256 * 64];
    __shared__ __attribute__((aligned(128))) unsigned char Bs8[2 * 256 * 64];

    const int z = blockIdx.x;        // XCD i owns batch i
    const int jb = blockIdx.y, ib = blockIdx.z;
    const unsigned char* __restrict__ Ab = A + (size_t)z * sA;
    const unsigned char* __restrict__ Bb = B + (size_t)z * sB;
    const int i0 = ib * 256, j0 = jb * 256;
    const int tid = threadIdx.x;
    const int w = tid >> 6, lane = tid & 63;
    const int wr = w >> 2, wc = w & 3;
    const int c16 = lane & 15, kq = lane >> 4;

    // staging: thread t -> row t>>2 (+128), stored slot t&3,
    // logical chunk p = (t&3) ^ (row&3) ^ ((row>>2)&1); row+128 keeps p.
    const int srow = tid >> 2;
    const int p8 = (tid & 3) ^ (srow & 3) ^ ((srow >> 2) & 1);
    const unsigned char* pa8 = Ab + (size_t)(i0 + srow) * lda + p8 * 16;
    const unsigned char* pb8 = Bb + (size_t)(j0 + srow) * ldb + p8 * 16;
    const size_t lda128 = (size_t)128 * lda, ldb128 = (size_t)128 * ldb;

    const unsigned wA8 = lds_off(As8) + (unsigned)tid * 16;
    const unsigned wB8 = lds_off(Bs8) + (unsigned)tid * 16;

    // frag read bases
    const int gl = (c16 & 3) ^ ((c16 >> 2) & 1);
    const int soff = ((((kq >> 1) ^ gl) << 4) | ((kq & 1) << 3));
    const unsigned adrA80 = lds_off(As8) + (unsigned)(wr * 128 + c16) * 64 + soff;
    const unsigned adrB80 = lds_off(Bs8) + (unsigned)(wc * 64 + c16) * 64 + soff;

    f32x4 acc[8][4];
    const f32x4 zero = {0.f, 0.f, 0.f, 0.f};
#pragma unroll
    for (int i = 0; i < 8; ++i)
#pragma unroll
        for (int j = 0; j < 4; ++j) acc[i][j] = zero;

    u32x4 fa0, fa1, fb0, fb1, ga0, ga1, gb0, gb1;
    long aL[4][2], aH[4][2], bF[4][2];

    const int nt = Kd >> 6;  // 12; requires even, >= 4

    // prologue: F<-t0, G<-t1; wait F; write t0->buf0; F<-t2
    LOADT8F(0);
    LOADT8G(1);
    VMC4;
    WRITET8F(0u);
    LOADT8F(2);
    LGKM(0);
    wg_barrier();

    for (int u = 0; u < nt / 2; ++u) {
        const int t0 = 2 * u;
        TILE8(0u, 16384u, WRITET8G, LOADT8G, t0);          // even tile: buf0
        TILE8(16384u, 0u, WRITET8F, LOADT8F, t0 + 1);      // odd tile: buf1
    }

    // epilogue: E = exp(sqrt(max(q2+k2-2*acc,0))*invs) -> bf16 (transposed
    // coalesced store) + fused row-sum into lsum (shfl over c16 + atomicAdd).
    unsigned short* C = Cq + (size_t)z * sC;
    const float* q2b = q2a + (size_t)z * sQ2;
    const float* k2b = k2a + (size_t)z * sK2;
    float* lz = lsum + (size_t)z * 2048;
    unsigned short* sc = (unsigned short*)(As8 + w * 4096);  // 16x72 shorts
    const int prow = kq * 4;
    const int rr = lane >> 3, ch = lane & 7;
#pragma unroll
    for (int mi = 0; mi < 8; ++mi) {
        float ev[4][4];
#pragma unroll
        for (int ni = 0; ni < 4; ++ni) {
            const int col = j0 + wc * 64 + ni * 16 + c16;
            const float k2v = k2b[col];
#pragma unroll
            for (int r = 0; r < 4; ++r) {
                const int grow = i0 + wr * 128 + mi * 16 + prow + r;
                float d2 = q2b[grow] + k2v - 2.0f * acc[mi][ni][r];
                ev[ni][r] = __expf(sqrtf(fmaxf(d2, 0.f)) * invs);
            }
        }
        // fused lsum: per (r): sum 4 ni then reduce over 16 c16 lanes
#pragma unroll
        for (int r = 0; r < 4; ++r) {
            float s = ev[0][r] + ev[1][r] + ev[2][r] + ev[3][r];
#pragma unroll
            for (int m = 1; m < 16; m <<= 1) s += __shfl_xor(s, m);
            if (c16 == 0)
                atomicAdd(lz + i0 + wr * 128 + mi * 16 + prow + r, s);
        }
#pragma unroll
        for (int ni = 0; ni < 4; ++ni)
#pragma unroll
            for (int r = 0; r < 4; ++r)
                sc[(prow + r) * 72 + ni * 16 + c16] = f2b(ev[ni][r]);
#pragma unroll
        for (int pass = 0; pass < 2; ++pass) {
            const int r2 = rr + 8 * pass;
            bf16x8 v = *(const bf16x8*)&sc[r2 * 72 + ch * 8];
            const int grow = i0 + wr * 128 + mi * 16 + r2;
            *(bf16x8*)&C[(size_t)grow * ldc + j0 + wc * 64 + ch * 8] = v;
        }
    }
}

extern "C" void kernel_launch(void* const* d_in, const int* in_sizes, int n_in,
                              void* d_out, int out_size, void* d_ws, size_t ws_size,
                              hipStream_t stream) {
    const float* x = (const float*)d_in[0];
    const float* Wq = (const float*)d_in[1];
    const float* Wk = (const float*)d_in[2];
    const float* Wv = (const float*)d_in[3];
    const int Bz = 8, S = 2048, D = 768, F = 768;
    const int BS = Bz * S;  // 16384

    const size_t szX = (size_t)BS * D * 2;
    const size_t szW = (size_t)F * D * 2;
    const size_t szQ8 = (size_t)BS * F;
    const size_t szE = (size_t)Bz * S * S * 2;

    char* p = (char*)d_ws;
    unsigned short* xb = (unsigned short*)p;  p += szX;
    unsigned short* Wqb = (unsigned short*)p; p += szW;
    unsigned short* Wkb = (unsigned short*)p; p += szW;
    unsigned short* Wvb = (unsigned short*)p; p += szW;
    unsigned char* Q8 = (unsigned char*)p;    p += szQ8;
    unsigned char* K8 = (unsigned char*)p;    p += szQ8;
    unsigned short* VT = (unsigned short*)p;  p += szX;   // [F][BS]
    unsigned short* E = (unsigned short*)p;   p += szE;   // [Bz][S][S]
    float* q2 = (float*)p;   p += (size_t)BS * 4;
    float* k2 = (float*)p;   p += (size_t)BS * 4;
    float* lsum = (float*)p; p += (size_t)BS * 4;
    if ((size_t)(p - (char*)d_ws) > ws_size) return;  // ~147 MiB scratch required

    const float invs = 1.0f / sqrtf(768.0f);

    // 1) casts + lsum zero
    castk<<<(BS * D / 4 + 255) / 256, 256, 0, stream>>>(x, xb, BS * D / 4);
    castk<<<(F * D / 4 + 255) / 256, 256, 0, stream>>>(Wq, Wqb, F * D / 4);
    castk<<<(F * D / 4 + 255) / 256, 256, 0, stream>>>(Wk, Wkb, F * D / 4);
    castk<<<(F * D / 4 + 255) / 256, 256, 0, stream>>>(Wv, Wvb, F * D / 4);
    zerok<<<BS / 256, 256, 0, stream>>>(lsum, BS);

    // 2) Q8,K8 = e4m3(x . W^T)  (z=0 -> Wq->Q8, z=1 -> Wk->K8)
    gemm256<3><<<dim3(F / 256, BS / 256, 2), 512, 0, stream>>>(
        xb, D, 0,
        Wqb, D, (long long)F * D,
        Q8, F, (long long)BS * F,
        D, 0, nullptr, 0);

    //    V^T = Wv . x^T   -> VT[f][s] (bf16)
    gemm256<0><<<dim3(BS / 256, F / 256, 1), 512, 0, stream>>>(
        Wvb, D, 0,
        xb, D, 0,
        VT, BS, 0,
        D, 0, nullptr, 0);

    // 3) q2,k2 from the fp8-rounded values
    rowreduce8<<<BS / 4, 256, 0, stream>>>(Q8, F, BS, q2);
    rowreduce8<<<BS / 4, 256, 0, stream>>>(K8, F, BS, k2);

    // 4) E + fused lsum; x=batch -> XCD-pinned
    gemm256f8<<<dim3(Bz, S / 256, S / 256), 512, 0, stream>>>(
        Q8, F, (long long)S * F,
        K8, F, (long long)S * F,
        E, S, (long long)S * S,
        F, q2, S, k2, S, lsum, invs);

    // 5) out = (E . V) / l; x=batch -> XCD reads the E_z it just wrote
    gemm256<2><<<dim3(Bz, F / 256, S / 256), 512, 0, stream>>>(
        E, S, (long long)S * S,
        VT, BS, (long long)S,
        d_out, F, (long long)S * F,
        S, 1, lsum, S);
}